// Round 12
// baseline (634.697 us; speedup 1.0000x reference)
//
#include <hip/hip_runtime.h>
#include <math.h>

#define WT 64
#define NWIN 1344
#define NP 1408  // padded key dim for PV GEMM
constexpr float SCALE = 0.088388347648318447f;  // 128^-0.5

// out region offsets (floats)
#define OUT0 0
#define OUT1 2097152
#define OUT2 10485760

typedef __attribute__((ext_vector_type(8))) short bfrag;      // 8 bf16
typedef __attribute__((ext_vector_type(8))) _Float16 hfrag;   // 8 fp16
typedef __attribute__((ext_vector_type(4))) float f32x4;      // MFMA C/D

#define MFMA16 __builtin_amdgcn_mfma_f32_16x16x32_bf16
#define MFMA16H __builtin_amdgcn_mfma_f32_16x16x32_f16

__device__ __forceinline__ unsigned short f2b(float f) {
    union { float f; unsigned u; } v; v.f = f;
    unsigned r = v.u + 0x7fffu + ((v.u >> 16) & 1u);  // rne
    return (unsigned short)(r >> 16);
}
__device__ __forceinline__ float b2f(unsigned short u) {
    union { unsigned u; float f; } v; v.u = ((unsigned)u) << 16; return v.f;
}
__device__ __forceinline__ int pack2(float a, float b) {
    return (int)f2b(a) | ((int)f2b(b) << 16);
}

// swizzled LDS fragment loads: row-major bf16 tiles, byte ^= (row&7)<<4
__device__ __forceinline__ bfrag ld256(const char* region, int row, int k) {
    int off = (2 * k) ^ ((row & 7) << 4);
    return *(const bfrag*)(region + row * 256 + off);
}
__device__ __forceinline__ bfrag ld128(const char* region, int row, int k) {
    int off = (2 * k) ^ ((row & 7) << 4);
    return *(const bfrag*)(region + row * 128 + off);
}

// K1: Mglob = Wq @ Wk^T (fp32, global path)
__global__ void k_mm(const float* __restrict__ Wq, const float* __restrict__ Wk,
                     float* __restrict__ Mglob) {
    int i = blockIdx.x, j = threadIdx.x;
    float acc = 0.f;
    for (int k = 0; k < 128; ++k) acc += Wq[i * 128 + k] * Wk[j * 128 + k];
    Mglob[i * 128 + j] = acc;
}

// K1b: bf16 transposed weight prep for local path (+ gate G0).
__global__ void k_prep(const float* __restrict__ Wql, const float* __restrict__ Wkl,
                       const float* __restrict__ Wvl, const float* __restrict__ gw,
                       unsigned short* __restrict__ MtB,
                       unsigned short* __restrict__ WvltB,
                       unsigned short* __restrict__ G1tB,
                       unsigned short* __restrict__ G0tB) {
    int n = blockIdx.x, k = threadIdx.x;
    if (blockIdx.y == 0) {
        float a = 0.f;
        for (int c = 0; c < 128; ++c) a += Wkl[n * 128 + c] * Wql[k * 128 + c];
        MtB[n * 128 + k] = f2b(a);
    } else if (blockIdx.y == 1) {
        WvltB[n * 128 + k] = f2b(Wvl[k * 128 + n]);
    } else if (blockIdx.y == 2) {
        G1tB[n * 128 + k] = f2b(gw[(128 + k) * 128 + n]);
    } else {
        G0tB[n * 128 + k] = f2b(gw[k * 128 + n]);
    }
}

// K1c: conv weight prep -> fp16 image [36 slices][512 oc][32 k]
__global__ __launch_bounds__(256) void k_prep_conv(
    const float* __restrict__ w0, const float* __restrict__ w1,
    _Float16* __restrict__ W0, _Float16* __restrict__ W1) {
    int idx = blockIdx.x * 256 + threadIdx.x;  // < 589824 = 36*512*32
    const float* w = blockIdx.y ? w1 : w0;
    _Float16* o = blockIdx.y ? W1 : W0;
    int slice = idx >> 14, rem = idx & 16383;
    int oc = rem >> 5, k = rem & 31;
    int ics = slice / 9, tap = slice - ics * 9;
    o[idx] = (_Float16)w[((size_t)oc * 128 + ics * 32 + k) * 9 + tap];
}

__device__ __forceinline__ void window_src(int n0, const float* f0, const float* f1,
                                           const float* f2, const float*& f, int& p0,
                                           int& HW, int& obase) {
    if (n0 < 4096)        { f = f0; p0 = n0;          HW = 4096;  obase = OUT0; }
    else if (n0 < 20480)  { f = f1; p0 = n0 - 4096;   HW = 16384; obase = OUT1; }
    else                  { f = f2; p0 = n0 - 20480;  HW = 65536; obase = OUT2; }
}

// K2: window means -> centers f32 [B,NWIN,128] + bf16 copy
__global__ __launch_bounds__(256) void k_centers(
    const float* __restrict__ f0, const float* __restrict__ f1,
    const float* __restrict__ f2, float* __restrict__ ctr,
    unsigned short* __restrict__ ctrb) {
    int w = blockIdx.x, b = blockIdx.y;
    const float* f; int p0, HW, ob;
    window_src(w * WT, f0, f1, f2, f, p0, HW, ob);
    int lane = threadIdx.x & 63, cg = threadIdx.x >> 6;
    for (int c = cg; c < 128; c += 4) {
        float v = f[(b * 128 + c) * HW + p0 + lane];
        #pragma unroll
        for (int off = 32; off; off >>= 1) v += __shfl_xor(v, off);
        if (lane == 0) {
            float mv = v * (1.0f / 64.0f);
            ctr[(b * NWIN + w) * 128 + c] = mv;
            ctrb[(b * NWIN + w) * 128 + c] = f2b(mv);
        }
    }
}

// K3: Tgb = bf16(centers @ Mglob) ; Vgt = bf16((centers @ Wv)^T) [c][NP]
__global__ __launch_bounds__(128) void k_tgvg(
    const float* __restrict__ ctr, const float* __restrict__ Mglob,
    const float* __restrict__ Wv, unsigned short* __restrict__ Tgb,
    unsigned short* __restrict__ Vgt) {
    int n = blockIdx.x, b = blockIdx.y;
    int row = b * NWIN + n;
    int c = threadIdx.x;
    __shared__ __align__(16) float crow[128];
    crow[c] = ctr[row * 128 + c];
    __syncthreads();
    float a1 = 0.f, a2 = 0.f;
    for (int k = 0; k < 128; ++k) {
        float cv = crow[k];
        a1 += cv * Mglob[k * 128 + c];
        a2 += cv * Wv[k * 128 + c];
    }
    Tgb[row * 128 + c] = f2b(a1);
    Vgt[((size_t)b * 128 + c) * NP + n] = f2b(a2);
}

// K4a: global scores + fused row softmax -> P bf16 [b][NWIN][NP] (pad zeroed)
__global__ __launch_bounds__(256, 1) void k_qk(
    const unsigned short* __restrict__ Tgb, const unsigned short* __restrict__ ctrb,
    unsigned short* __restrict__ P) {
    extern __shared__ unsigned short Srow[];  // [32][1344] bf16 raw scores
    __shared__ float mxs[32], invs[32];
    int blk = blockIdx.x, b = blockIdx.y;
    int mb = blk * 32;
    int tid = threadIdx.x, wid = tid >> 6, lane = tid & 63;
    int lr = lane & 15, lg = lane >> 4;
    int wm = (wid & 1) * 16, wn = (wid >> 1) * 32;

    const unsigned short* Arow = Tgb + ((size_t)b * NWIN + mb + wm + lr) * 128;
    for (int tile = 0; tile < 21; ++tile) {
        int nb = tile * 64 + wn;
        f32x4 acc[2] = {};
        #pragma unroll
        for (int ks = 0; ks < 4; ++ks) {
            int k = ks * 32 + lg * 8;
            bfrag a = *(const bfrag*)(Arow + k);
            #pragma unroll
            for (int nt = 0; nt < 2; ++nt) {
                bfrag bb = *(const bfrag*)(ctrb + ((size_t)b * NWIN + nb + nt * 16 + lr) * 128 + k);
                acc[nt] = MFMA16(a, bb, acc[nt], 0, 0, 0);
            }
        }
        #pragma unroll
        for (int nt = 0; nt < 2; ++nt) {
            int col = nb + nt * 16 + lr;
            #pragma unroll
            for (int r = 0; r < 4; ++r) {
                int mrow = wm + 4 * lg + r;
                Srow[mrow * 1344 + col] = f2b(acc[nt][r]);
            }
        }
    }
    __syncthreads();
    {   // row max + sum(exp): 8 threads per row
        int row = tid >> 3, sub = tid & 7;
        const unsigned short* sr = Srow + row * 1344;
        float mx = -1e30f;
        for (int c = sub; c < 1344; c += 8) mx = fmaxf(mx, b2f(sr[c]));
        mx = fmaxf(mx, __shfl_xor(mx, 1));
        mx = fmaxf(mx, __shfl_xor(mx, 2));
        mx = fmaxf(mx, __shfl_xor(mx, 4));
        float sum = 0.f;
        for (int c = sub; c < 1344; c += 8) sum += __expf((b2f(sr[c]) - mx) * SCALE);
        sum += __shfl_xor(sum, 1);
        sum += __shfl_xor(sum, 2);
        sum += __shfl_xor(sum, 4);
        if (sub == 0) { mxs[row] = mx; invs[row] = 1.0f / sum; }
    }
    __syncthreads();
    unsigned short* Pb = P + ((size_t)b * NWIN + mb) * NP;
    for (int idx = tid; idx < 32 * (NP / 8); idx += 256) {
        int row = idx / (NP / 8), c8 = idx % (NP / 8);
        float mx = mxs[row], inv = invs[row];
        unsigned short o[8];
        #pragma unroll
        for (int e = 0; e < 8; ++e) {
            int c = c8 * 8 + e;
            float p = (c < 1344) ? __expf((b2f(Srow[row * 1344 + c]) - mx) * SCALE) * inv : 0.f;
            o[e] = f2b(p);
        }
        *(int4*)(Pb + row * NP + c8 * 8) = *(int4*)o;
    }
}

// K4b: Y^T = Vgt x P^T (register-only MFMA GEMM); ycen = Y * centers (+bf16 copy)
__global__ __launch_bounds__(256) void k_pv(
    const unsigned short* __restrict__ P, const unsigned short* __restrict__ Vgt,
    const float* __restrict__ ctr, float* __restrict__ ycen,
    unsigned short* __restrict__ ycenb) {
    int blk = blockIdx.x, b = blockIdx.y;
    int mb = blk * 32;
    int tid = threadIdx.x, wid = tid >> 6, lane = tid & 63;
    int lr = lane & 15, lg = lane >> 4;
    int cb = wid * 32;
    f32x4 acc[2][2] = {};  // [ci][mj]
    const unsigned short* Pb = P + ((size_t)b * NWIN + mb) * NP;
    const unsigned short* Vb = Vgt + (size_t)b * 128 * NP;
    for (int it = 0; it < 44; ++it) {
        int k = it * 32 + lg * 8;
        bfrag a0 = *(const bfrag*)(Vb + (size_t)(cb + lr) * NP + k);
        bfrag a1 = *(const bfrag*)(Vb + (size_t)(cb + 16 + lr) * NP + k);
        bfrag b0 = *(const bfrag*)(Pb + (size_t)lr * NP + k);
        bfrag b1 = *(const bfrag*)(Pb + (size_t)(16 + lr) * NP + k);
        acc[0][0] = MFMA16(a0, b0, acc[0][0], 0, 0, 0);
        acc[0][1] = MFMA16(a0, b1, acc[0][1], 0, 0, 0);
        acc[1][0] = MFMA16(a1, b0, acc[1][0], 0, 0, 0);
        acc[1][1] = MFMA16(a1, b1, acc[1][1], 0, 0, 0);
    }
    #pragma unroll
    for (int ci = 0; ci < 2; ++ci)
        #pragma unroll
        for (int mj = 0; mj < 2; ++mj) {
            int c0 = cb + ci * 16 + 4 * lg;
            int m = mb + mj * 16 + lr;
            size_t base = ((size_t)b * NWIN + m) * 128 + c0;
            float4 cv = *(const float4*)(ctr + base);
            float4 y;
            y.x = acc[ci][mj][0] * cv.x;
            y.y = acc[ci][mj][1] * cv.y;
            y.z = acc[ci][mj][2] * cv.z;
            y.w = acc[ci][mj][3] * cv.w;
            *(float4*)(ycen + base) = y;
            int2 pv; pv.x = pack2(y.x, y.y); pv.y = pack2(y.z, y.w);
            *(int2*)(ycenb + base) = pv;
        }
}

// K4c: g0 = ycen @ G0 (gate first half), tiny MFMA GEMM -> g0g f32
__global__ __launch_bounds__(256) void k_g0(
    const unsigned short* __restrict__ ycenb, const unsigned short* __restrict__ G0tB,
    float* __restrict__ g0g) {
    int blk = blockIdx.x, b = blockIdx.y;
    int mb = blk * 32;
    int tid = threadIdx.x, wid = tid >> 6, lane = tid & 63;
    int lr = lane & 15, lg = lane >> 4;
    int nb = wid * 32;
    f32x4 acc[2][2] = {};  // [ni][mj]
    const unsigned short* Yb = ycenb + ((size_t)b * NWIN + mb) * 128;
    #pragma unroll
    for (int ks = 0; ks < 4; ++ks) {
        int k = ks * 32 + lg * 8;
        bfrag a0 = *(const bfrag*)(G0tB + (nb + lr) * 128 + k);
        bfrag a1 = *(const bfrag*)(G0tB + (nb + 16 + lr) * 128 + k);
        bfrag b0 = *(const bfrag*)(Yb + lr * 128 + k);
        bfrag b1 = *(const bfrag*)(Yb + (16 + lr) * 128 + k);
        acc[0][0] = MFMA16(a0, b0, acc[0][0], 0, 0, 0);
        acc[0][1] = MFMA16(a0, b1, acc[0][1], 0, 0, 0);
        acc[1][0] = MFMA16(a1, b0, acc[1][0], 0, 0, 0);
        acc[1][1] = MFMA16(a1, b1, acc[1][1], 0, 0, 0);
    }
    #pragma unroll
    for (int ni = 0; ni < 2; ++ni)
        #pragma unroll
        for (int mj = 0; mj < 2; ++mj) {
            int m = mb + mj * 16 + lr;
            int n0 = nb + ni * 16 + 4 * lg;
            #pragma unroll
            for (int r = 0; r < 4; ++r)
                g0g[((size_t)b * NWIN + m) * 128 + n0 + r] = acc[ni][mj][r];
        }
}

// ---------- K5: fused local window attention via MFMA (80 KB, 2 blocks/CU) ----
// 5 compute barriers + 1 epilogue barrier. Result staged through the dead
// XMb+Vt region (32 KB) as [c][64t] f32 with 16B-chunk XOR swizzle, then
// stored as contiguous 128B half-rows per thread (fixes 2x write amplification).
#define XB_OFF 0
#define WT_OFF 16384
#define XM_OFF 49152
#define VT_OFF 65536
#define SMEM_SZ 81920

__global__ __launch_bounds__(256, 2) void k_local_mfma(
    const float* __restrict__ f0, const float* __restrict__ f1,
    const float* __restrict__ f2,
    const unsigned short* __restrict__ MtB,
    const unsigned short* __restrict__ WvltB,
    const unsigned short* __restrict__ G1tB,
    const float* __restrict__ g0g, const float* __restrict__ ycen,
    float* __restrict__ out) {
    extern __shared__ char smem[];
    char* Xb = smem + XB_OFF;    // X; yl in-place during phase 4
    char* Wt = smem + WT_OFF;    // Mt -> Wvlt -> G1t
    char* XMb = smem + XM_OFF;   // XM; P in row t's first 128 B; sres in phase 5
    char* Vt = smem + VT_OFF;

    int w = blockIdx.x, b = blockIdx.y;
    const float* f; int p0, HW, obase;
    window_src(w * WT, f0, f1, f2, f, p0, HW, obase);

    int tid = threadIdx.x;
    int wid = tid >> 6, lane = tid & 63;
    int lr = lane & 15, lg = lane >> 4;

    // ---- phase 0: stage X (f32->bf16 swizzled) + Mt weights ----
    {
        int t0 = tid & 63, cq = tid >> 6;
        const float* src = f + (size_t)(b * 128 + cq * 32) * HW + p0 + t0;
        float xv[32];
        #pragma unroll
        for (int i = 0; i < 32; ++i) xv[i] = src[(size_t)i * HW];
        int4 wreg[8];
        const int4* wsrc = (const int4*)MtB;
        #pragma unroll
        for (int j = 0; j < 8; ++j) wreg[j] = wsrc[j * 256 + tid];
        #pragma unroll
        for (int j = 0; j < 4; ++j) {
            int c0 = cq * 32 + j * 8;
            int4 v;
            v.x = pack2(xv[j * 8 + 0], xv[j * 8 + 1]);
            v.y = pack2(xv[j * 8 + 2], xv[j * 8 + 3]);
            v.z = pack2(xv[j * 8 + 4], xv[j * 8 + 5]);
            v.w = pack2(xv[j * 8 + 6], xv[j * 8 + 7]);
            *(int4*)(Xb + t0 * 256 + ((2 * c0) ^ ((t0 & 7) << 4))) = v;
        }
        #pragma unroll
        for (int j = 0; j < 8; ++j) {
            int ci = j * 256 + tid, n = ci >> 4, pos = ci & 15;
            *(int4*)(Wt + n * 256 + ((pos * 16) ^ ((n & 7) << 4))) = wreg[j];
        }
    }
    __syncthreads();  // B1

    int t = 16 * wid + lr;

    // ---- phase 1: XM^T = Mt(A,LDS) x X(B) -> XMb (wave-private rows) ----
    {
        f32x4 acc[8] = {};
        #pragma unroll
        for (int ks = 0; ks < 4; ++ks) {
            int k = ks * 32 + lg * 8;
            bfrag xb = ld256(Xb, t, k);
            #pragma unroll
            for (int ct = 0; ct < 8; ++ct) {
                bfrag am = ld256(Wt, 16 * ct + lr, k);
                acc[ct] = MFMA16(am, xb, acc[ct], 0, 0, 0);
            }
        }
        #pragma unroll
        for (int ct = 0; ct < 8; ++ct) {
            int c0 = 16 * ct + 4 * lg;
            int2 v; v.x = pack2(acc[ct][0], acc[ct][1]); v.y = pack2(acc[ct][2], acc[ct][3]);
            *(int2*)(XMb + t * 256 + ((2 * c0) ^ ((t & 7) << 4))) = v;
        }
    }
    __syncthreads();  // B2 (Mt reads done everywhere; XM rows are wave-private)

    // ---- phase 2: S^T + softmax; P overwrites own XM row (no barrier); Wvlt ----
    {
        int4 wreg[8];
        const int4* wsrc = (const int4*)WvltB;
        #pragma unroll
        for (int j = 0; j < 8; ++j) wreg[j] = wsrc[j * 256 + tid];

        f32x4 s[4] = {};
        #pragma unroll
        for (int ks = 0; ks < 4; ++ks) {
            int k = ks * 32 + lg * 8;
            bfrag bxm = ld256(XMb, t, k);
            #pragma unroll
            for (int ut = 0; ut < 4; ++ut) {
                bfrag ax = ld256(Xb, 16 * ut + lr, k);
                s[ut] = MFMA16(ax, bxm, s[ut], 0, 0, 0);
            }
        }
        float m = -1e30f;
        #pragma unroll
        for (int ut = 0; ut < 4; ++ut)
            #pragma unroll
            for (int r = 0; r < 4; ++r) m = fmaxf(m, s[ut][r]);
        m = fmaxf(m, __shfl_xor(m, 16));
        m = fmaxf(m, __shfl_xor(m, 32));
        float sum = 0.f;
        float e[4][4];
        #pragma unroll
        for (int ut = 0; ut < 4; ++ut)
            #pragma unroll
            for (int r = 0; r < 4; ++r) {
                e[ut][r] = __expf((s[ut][r] - m) * SCALE);
                sum += e[ut][r];
            }
        sum += __shfl_xor(sum, 16);
        sum += __shfl_xor(sum, 32);
        float pinv = 1.0f / sum;
        // P write into OWN XM row t (wave-private) — no block barrier needed.
        #pragma unroll
        for (int ut = 0; ut < 4; ++ut) {
            int u0 = 16 * ut + 4 * lg;
            int2 v;
            v.x = pack2(e[ut][0] * pinv, e[ut][1] * pinv);
            v.y = pack2(e[ut][2] * pinv, e[ut][3] * pinv);
            *(int2*)(XMb + t * 256 + ((2 * u0) ^ ((t & 7) << 4))) = v;
        }
        #pragma unroll
        for (int j = 0; j < 8; ++j) {
            int ci = j * 256 + tid, n = ci >> 4, pos = ci & 15;
            *(int4*)(Wt + n * 256 + ((pos * 16) ^ ((n & 7) << 4))) = wreg[j];
        }
    }
    __syncthreads();  // B3 (Wvlt visible)

    // ---- phase 3: V^T = X(A) x Wvlt(B,LDS) -> Vt; issue G1t loads ----
    int4 wregG[8];
    {
        const int4* wsrc = (const int4*)G1tB;
        #pragma unroll
        for (int j = 0; j < 8; ++j) wregG[j] = wsrc[j * 256 + tid];

        f32x4 vacc[8] = {};
        #pragma unroll
        for (int ks = 0; ks < 4; ++ks) {
            int k = ks * 32 + lg * 8;
            bfrag ax = ld256(Xb, t, k);
            #pragma unroll
            for (int ct = 0; ct < 8; ++ct) {
                bfrag bw = ld256(Wt, 16 * ct + lr, k);
                vacc[ct] = MFMA16(ax, bw, vacc[ct], 0, 0, 0);
            }
        }
        #pragma unroll
        for (int ct = 0; ct < 8; ++ct) {
            int c = 16 * ct + lr;
            int u0 = 16 * wid + 4 * lg;
            int2 v; v.x = pack2(vacc[ct][0], vacc[ct][1]); v.y = pack2(vacc[ct][2], vacc[ct][3]);
            *(int2*)(Vt + c * 128 + ((2 * u0) ^ ((c & 7) << 4))) = v;
        }
    }
    __syncthreads();  // B4 (Wvlt reads done; Vt visible)

    // ---- phase 4: stage G1t; Y^T = Vt(A) x P(B); yl = Y*X in-place; yg/g0 ----
    float yl[8][4];
    float4 yg4[8], g04[8];
    {
        #pragma unroll
        for (int j = 0; j < 8; ++j) {
            int ci = j * 256 + tid, n = ci >> 4, pos = ci & 15;
            *(int4*)(Wt + n * 256 + ((pos * 16) ^ ((n & 7) << 4))) = wregG[j];
        }
        size_t rbase = ((size_t)b * NWIN + w) * 128 + 4 * lg;
        #pragma unroll
        for (int nt = 0; nt < 8; ++nt) {
            yg4[nt] = *(const float4*)(ycen + rbase + 16 * nt);
            g04[nt] = *(const float4*)(g0g + rbase + 16 * nt);
        }
        f32x4 y[8] = {};
        #pragma unroll
        for (int us = 0; us < 2; ++us) {
            int u = us * 32 + lg * 8;
            bfrag bp = ld256(XMb, t, u);  // P (stride-256, own row)
            #pragma unroll
            for (int ct = 0; ct < 8; ++ct) {
                bfrag av = ld128(Vt, 16 * ct + lr, u);
                y[ct] = MFMA16(av, bp, y[ct], 0, 0, 0);
            }
        }
        #pragma unroll
        for (int ct = 0; ct < 8; ++ct) {
            int c0 = 16 * ct + 4 * lg;
            int2 xw = *(const int2*)(Xb + t * 256 + ((2 * c0) ^ ((t & 7) << 4)));
            float x0 = b2f((unsigned short)(xw.x & 0xffff));
            float x1 = b2f((unsigned short)((unsigned)xw.x >> 16));
            float x2 = b2f((unsigned short)(xw.y & 0xffff));
            float x3 = b2f((unsigned short)((unsigned)xw.y >> 16));
            yl[ct][0] = y[ct][0] * x0;
            yl[ct][1] = y[ct][1] * x1;
            yl[ct][2] = y[ct][2] * x2;
            yl[ct][3] = y[ct][3] * x3;
            int2 v; v.x = pack2(yl[ct][0], yl[ct][1]); v.y = pack2(yl[ct][2], yl[ct][3]);
            *(int2*)(Xb + t * 256 + ((2 * c0) ^ ((t & 7) << 4))) = v;  // in-place yl
        }
    }
    __syncthreads();  // B5 (G1t + yl visible; XMb/Vt now dead -> sres)

    // ---- phase 5: G^T = G1t(A,LDS) x yl(B); alpha; blend -> sres ----
    {
        f32x4 g[8] = {};
        #pragma unroll
        for (int ks = 0; ks < 4; ++ks) {
            int k = ks * 32 + lg * 8;
            bfrag byl = ld256(Xb, t, k);  // yl
            #pragma unroll
            for (int nt = 0; nt < 8; ++nt) {
                bfrag ag = ld256(Wt, 16 * nt + lr, k);
                g[nt] = MFMA16(ag, byl, g[nt], 0, 0, 0);
            }
        }
        float* sres = (float*)(smem + XM_OFF);  // 32 KB [c][64 t], 16B-chunk swz
        #pragma unroll
        for (int nt = 0; nt < 8; ++nt) {
            float gv[4] = {g04[nt].x, g04[nt].y, g04[nt].z, g04[nt].w};
            float yv4[4] = {yg4[nt].x, yg4[nt].y, yg4[nt].z, yg4[nt].w};
            #pragma unroll
            for (int r = 0; r < 4; ++r) {
                int c = 16 * nt + 4 * lg + r;
                float a = 1.0f / (1.0f + __expf(-(g[nt][r] + gv[r])));
                float yv = a * yv4[r] + (1.0f - a) * yl[nt][r];
                int chunk = (t >> 2) ^ (c & 7);
                sres[c * 64 + chunk * 4 + (t & 3)] = yv;
            }
        }
    }
    __syncthreads();  // B6 (sres complete)

    // ---- epilogue: coalesced store, 128B contiguous per thread ----
    {
        const float* sres = (const float*)(smem + XM_OFF);
        int c = tid >> 1, half = tid & 1;
        float4 v[8];
        #pragma unroll
        for (int j = 0; j < 8; ++j) {
            int lc = half * 8 + j;
            v[j] = *(const float4*)(sres + c * 64 + ((lc ^ (c & 7)) * 4));
        }
        float* gbase = out + obase + (size_t)(b * 128 + c) * HW + p0 + half * 32;
        #pragma unroll
        for (int j = 0; j < 8; ++j)
            *(float4*)(gbase + j * 4) = v[j];
    }
}

// ---------- K6/K7 v4: conv3x3 + PixelShuffle + residual, MFMA fp16 ----------
// Weights never touch LDS: register double-buffered direct-L2 A-fragments.
template <int H, int W>
__global__ __launch_bounds__(256, 2) void k_conv_mfma(
    const float* __restrict__ in, const _Float16* __restrict__ Wcv,
    float* __restrict__ out) {
    constexpr int TXN = W / 32;
    int tile = blockIdx.x;
    int ty = tile / TXN, tx = tile % TXN;
    int y0 = ty * 4, x0 = tx * 32;
    int ob = blockIdx.y * 256;
    int b = blockIdx.z;

    __shared__ __align__(16) char sXs[16384];  // 204 rows x 80B, slot swz (row>>3)&1

    int tid = threadIdx.x;
    int wid = tid >> 6, lane = tid & 63;
    int lr = lane & 15, lg = lane >> 4;

    f32x4 acc[8][4] = {};

    int sy = tid / 34, sx = tid - sy * 34;
    int gy = y0 + sy - 1, gx = x0 + sx - 1;
    bool act = tid < 204;
    bool ok = act && gy >= 0 && gy < H && gx >= 0 && gx < W;
    const float* gp = in + (size_t)b * 128 * H * W + (size_t)gy * W + gx;
    int xswz = (tid >> 3) & 1;

    const _Float16* wbase = Wcv + (size_t)(ob + lr) * 32 + lg * 8;

    hfrag afC[4], afN[4];
    #pragma unroll
    for (int n = 0; n < 4; ++n)
        afC[n] = *(const hfrag*)(wbase + (size_t)(wid * 4 + n) * 512);

    if (act) {
        float xv[32];
        if (ok) {
            #pragma unroll
            for (int ic = 0; ic < 32; ++ic) xv[ic] = gp[(size_t)ic * H * W];
        } else {
            #pragma unroll
            for (int ic = 0; ic < 32; ++ic) xv[ic] = 0.f;
        }
        #pragma unroll
        for (int s = 0; s < 4; ++s) {
            _Float16 hh[8];
            #pragma unroll
            for (int e = 0; e < 8; ++e) hh[e] = (_Float16)xv[s * 8 + e];
            *(int4*)(sXs + tid * 80 + ((s ^ xswz) << 4)) = *(int4*)hh;
        }
    }
    __syncthreads();

    for (int ics = 0; ics < 4; ++ics) {
        if (ics) {
            __syncthreads();
            if (act) {
                float xv[32];
                if (ok) {
                    #pragma unroll
                    for (int ic = 0; ic < 32; ++ic)
                        xv[ic] = gp[(size_t)(ics * 32 + ic) * H * W];
                } else {
                    #pragma unroll
                    for (int ic = 0; ic < 32; ++ic) xv[ic] = 0.f;
                }
                #pragma unroll
                for (int s = 0; s < 4; ++s) {
                    _Float16 hh[8];
                    #pragma unroll
                    for (int e = 0; e < 8; ++e) hh[e] = (_Float16)xv[s * 8 + e];
                    *(int4*)(sXs + tid * 80 + ((s ^ xswz) << 4)) = *(int4*)hh;
                }
            }
            __syncthreads();
        }
        #pragma unroll
        for (int tap = 0; tap < 9; ++tap) {
            int kg = ics * 9 + tap;
            if (tap < 8 || ics < 3) {
                const _Float16* ws = wbase + (size_t)(kg + 1) * 16384;
                #pragma unroll
                for (int n = 0; n < 4; ++n)
                    afN[n] = *(const hfrag*)(ws + (size_t)(wid * 4 + n) * 512);
            }
            int dy = tap / 3, dx = tap - dy * 3;
            hfrag bf[8];
            #pragma unroll
            for (int m = 0; m < 8; ++m) {
                int row = ((m >> 1) + dy) * 34 + (m & 1) * 16 + lr + dx;
                bf[m] = *(const hfrag*)(sXs + row * 80 + ((lg ^ ((row >> 3) & 1)) << 4));
            }
            #pragma unroll
            for (int m = 0; m < 8; ++m)
                #pragma unroll
                for (int n = 0; n < 4; ++n)
                    acc[m][n] = MFMA16H(afC[n], bf[m], acc[m][n], 0, 0, 0);
            #pragma unroll
            for (int n = 0; n < 4; ++n) afC[n] = afN[n];
        }
    }

    float* outb = out + (size_t)b * 128 * 4 * H * W;
    #pragma unroll
    for (int n = 0; n < 4; ++n) {
        int oc0 = ob + (wid * 4 + n) * 16 + lg * 4;
        int c = oc0 >> 2;
        #pragma unroll
        for (int mr = 0; mr < 4; ++mr) {
            int py = y0 + mr;
            #pragma unroll
            for (int i2 = 0; i2 < 2; ++i2) {
                size_t rowb = ((size_t)c * (2 * H) + 2 * py + i2) * (2 * W);
                float2* p0 = (float2*)(outb + rowb + 2 * (x0 + lr));
                float2 v0 = *p0;
                v0.x += acc[2 * mr][n][i2 * 2 + 0];
                v0.y += acc[2 * mr][n][i2 * 2 + 1];
                *p0 = v0;
                float2* p1 = (float2*)(outb + rowb + 2 * (x0 + 16 + lr));
                float2 v1 = *p1;
                v1.x += acc[2 * mr + 1][n][i2 * 2 + 0];
                v1.y += acc[2 * mr + 1][n][i2 * 2 + 1];
                *p1 = v1;
            }
        }
    }
}

extern "C" void kernel_launch(void* const* d_in, const int* in_sizes, int n_in,
                              void* d_out, int out_size, void* d_ws, size_t ws_size,
                              hipStream_t stream) {
    const float* f0 = (const float*)d_in[0];
    const float* f1 = (const float*)d_in[1];
    const float* f2 = (const float*)d_in[2];
    const float* Wq = (const float*)d_in[3];
    const float* Wk = (const float*)d_in[4];
    const float* Wv = (const float*)d_in[5];
    const float* Wql = (const float*)d_in[6];
    const float* Wkl = (const float*)d_in[7];
    const float* Wvl = (const float*)d_in[8];
    const float* gate_w = (const float*)d_in[9];
    const float* conv0 = (const float*)d_in[10];
    const float* conv1 = (const float*)d_in[11];
    float* out = (float*)d_out;
    float* ws = (float*)d_ws;

    float* Mglob = ws;                    // 16384 f32
    float* ctr = Mglob + 16384;           // 688128 f32
    float* ycen = ctr + 688128;           // 688128 f32
    float* g0g = ycen + 688128;           // 688128 f32
    unsigned short* MtB = (unsigned short*)(g0g + 688128);   // 16384 bf16
    unsigned short* WvltB = MtB + 16384;                     // 16384 bf16
    unsigned short* G1tB = WvltB + 16384;                    // 16384 bf16
    unsigned short* G0tB = G1tB + 16384;                     // 16384 bf16
    _Float16* Wcv0 = (_Float16*)(G0tB + 16384);              // 589824 f16
    _Float16* Wcv1 = Wcv0 + 589824;                          // 589824 f16
    unsigned short* ctrb = (unsigned short*)(Wcv1 + 589824); // 688128 bf16
    unsigned short* Tgb = ctrb + 688128;                     // 688128 bf16
    unsigned short* ycenb = Tgb + 688128;                    // 688128 bf16
    unsigned short* Vgt = ycenb + 688128;                    // 4*128*NP bf16
    unsigned short* Pg = Vgt + 4 * 128 * NP;                 // 4*NWIN*NP bf16

    hipFuncSetAttribute((const void*)k_local_mfma,
                        hipFuncAttributeMaxDynamicSharedMemorySize, SMEM_SZ);
    hipFuncSetAttribute((const void*)k_qk,
                        hipFuncAttributeMaxDynamicSharedMemorySize, 32 * 1344 * 2);

    k_mm<<<dim3(128), 128, 0, stream>>>(Wq, Wk, Mglob);
    k_prep<<<dim3(128, 4), 128, 0, stream>>>(Wql, Wkl, Wvl, gate_w, MtB, WvltB, G1tB, G0tB);
    k_prep_conv<<<dim3(2304, 2), 256, 0, stream>>>(conv0, conv1, Wcv0, Wcv1);
    k_centers<<<dim3(NWIN, 4), 256, 0, stream>>>(f0, f1, f2, ctr, ctrb);
    k_tgvg<<<dim3(NWIN, 4), 128, 0, stream>>>(ctr, Mglob, Wv, Tgb, Vgt);
    k_qk<<<dim3(NWIN / 32, 4), 256, 32 * 1344 * 2, stream>>>(Tgb, ctrb, Pg);
    k_pv<<<dim3(NWIN / 32, 4), 256, 0, stream>>>(Pg, Vgt, ctr, ycen, ycenb);
    k_g0<<<dim3(NWIN / 32, 4), 256, 0, stream>>>(ycenb, G0tB, g0g);
    k_local_mfma<<<dim3(NWIN, 4), 256, SMEM_SZ, stream>>>(
        f0, f1, f2, MtB, WvltB, G1tB, g0g, ycen, out);
    k_conv_mfma<64, 64><<<dim3(32, 2, 4), 256, 0, stream>>>(out + OUT0, Wcv0, out + OUT1);
    k_conv_mfma<128, 128><<<dim3(128, 2, 4), 256, 0, stream>>>(out + OUT1, Wcv1, out + OUT2);
}

// Round 13
// 595.253 us; speedup vs baseline: 1.0663x; 1.0663x over previous
//
#include <hip/hip_runtime.h>
#include <math.h>

#define WT 64
#define NWIN 1344
#define NP 1408  // padded key dim for PV GEMM
constexpr float SCALE = 0.088388347648318447f;  // 128^-0.5

// out region offsets (floats)
#define OUT0 0
#define OUT1 2097152
#define OUT2 10485760

typedef __attribute__((ext_vector_type(8))) short bfrag;      // 8 bf16
typedef __attribute__((ext_vector_type(8))) _Float16 hfrag;   // 8 fp16
typedef __attribute__((ext_vector_type(4))) float f32x4;      // MFMA C/D

#define MFMA16 __builtin_amdgcn_mfma_f32_16x16x32_bf16
#define MFMA16H __builtin_amdgcn_mfma_f32_16x16x32_f16

__device__ __forceinline__ unsigned short f2b(float f) {
    union { float f; unsigned u; } v; v.f = f;
    unsigned r = v.u + 0x7fffu + ((v.u >> 16) & 1u);  // rne
    return (unsigned short)(r >> 16);
}
__device__ __forceinline__ float b2f(unsigned short u) {
    union { unsigned u; float f; } v; v.u = ((unsigned)u) << 16; return v.f;
}
__device__ __forceinline__ int pack2(float a, float b) {
    return (int)f2b(a) | ((int)f2b(b) << 16);
}

// swizzled LDS fragment loads: row-major bf16 tiles, byte ^= (row&7)<<4
__device__ __forceinline__ bfrag ld256(const char* region, int row, int k) {
    int off = (2 * k) ^ ((row & 7) << 4);
    return *(const bfrag*)(region + row * 256 + off);
}
__device__ __forceinline__ bfrag ld128(const char* region, int row, int k) {
    int off = (2 * k) ^ ((row & 7) << 4);
    return *(const bfrag*)(region + row * 128 + off);
}

// K1: Mglob = Wq @ Wk^T (fp32, global path)
__global__ void k_mm(const float* __restrict__ Wq, const float* __restrict__ Wk,
                     float* __restrict__ Mglob) {
    int i = blockIdx.x, j = threadIdx.x;
    float acc = 0.f;
    for (int k = 0; k < 128; ++k) acc += Wq[i * 128 + k] * Wk[j * 128 + k];
    Mglob[i * 128 + j] = acc;
}

// K1b: bf16 transposed weight prep for local path (+ gate G0).
__global__ void k_prep(const float* __restrict__ Wql, const float* __restrict__ Wkl,
                       const float* __restrict__ Wvl, const float* __restrict__ gw,
                       unsigned short* __restrict__ MtB,
                       unsigned short* __restrict__ WvltB,
                       unsigned short* __restrict__ G1tB,
                       unsigned short* __restrict__ G0tB) {
    int n = blockIdx.x, k = threadIdx.x;
    if (blockIdx.y == 0) {
        float a = 0.f;
        for (int c = 0; c < 128; ++c) a += Wkl[n * 128 + c] * Wql[k * 128 + c];
        MtB[n * 128 + k] = f2b(a);
    } else if (blockIdx.y == 1) {
        WvltB[n * 128 + k] = f2b(Wvl[k * 128 + n]);
    } else if (blockIdx.y == 2) {
        G1tB[n * 128 + k] = f2b(gw[(128 + k) * 128 + n]);
    } else {
        G0tB[n * 128 + k] = f2b(gw[k * 128 + n]);
    }
}

// K1c: conv weight prep -> fp16 image [36 slices][512 oc][32 k]
__global__ __launch_bounds__(256) void k_prep_conv(
    const float* __restrict__ w0, const float* __restrict__ w1,
    _Float16* __restrict__ W0, _Float16* __restrict__ W1) {
    int idx = blockIdx.x * 256 + threadIdx.x;  // < 589824 = 36*512*32
    const float* w = blockIdx.y ? w1 : w0;
    _Float16* o = blockIdx.y ? W1 : W0;
    int slice = idx >> 14, rem = idx & 16383;
    int oc = rem >> 5, k = rem & 31;
    int ics = slice / 9, tap = slice - ics * 9;
    o[idx] = (_Float16)w[((size_t)oc * 128 + ics * 32 + k) * 9 + tap];
}

__device__ __forceinline__ void window_src(int n0, const float* f0, const float* f1,
                                           const float* f2, const float*& f, int& p0,
                                           int& HW, int& obase) {
    if (n0 < 4096)        { f = f0; p0 = n0;          HW = 4096;  obase = OUT0; }
    else if (n0 < 20480)  { f = f1; p0 = n0 - 4096;   HW = 16384; obase = OUT1; }
    else                  { f = f2; p0 = n0 - 20480;  HW = 65536; obase = OUT2; }
}

// K2: window means -> centers f32 [B,NWIN,128] + bf16 copy
__global__ __launch_bounds__(256) void k_centers(
    const float* __restrict__ f0, const float* __restrict__ f1,
    const float* __restrict__ f2, float* __restrict__ ctr,
    unsigned short* __restrict__ ctrb) {
    int w = blockIdx.x, b = blockIdx.y;
    const float* f; int p0, HW, ob;
    window_src(w * WT, f0, f1, f2, f, p0, HW, ob);
    int lane = threadIdx.x & 63, cg = threadIdx.x >> 6;
    for (int c = cg; c < 128; c += 4) {
        float v = f[(b * 128 + c) * HW + p0 + lane];
        #pragma unroll
        for (int off = 32; off; off >>= 1) v += __shfl_xor(v, off);
        if (lane == 0) {
            float mv = v * (1.0f / 64.0f);
            ctr[(b * NWIN + w) * 128 + c] = mv;
            ctrb[(b * NWIN + w) * 128 + c] = f2b(mv);
        }
    }
}

// K3: Tgb = bf16(centers @ Mglob) ; Vgt = bf16((centers @ Wv)^T) [c][NP]
__global__ __launch_bounds__(128) void k_tgvg(
    const float* __restrict__ ctr, const float* __restrict__ Mglob,
    const float* __restrict__ Wv, unsigned short* __restrict__ Tgb,
    unsigned short* __restrict__ Vgt) {
    int n = blockIdx.x, b = blockIdx.y;
    int row = b * NWIN + n;
    int c = threadIdx.x;
    __shared__ __align__(16) float crow[128];
    crow[c] = ctr[row * 128 + c];
    __syncthreads();
    float a1 = 0.f, a2 = 0.f;
    for (int k = 0; k < 128; ++k) {
        float cv = crow[k];
        a1 += cv * Mglob[k * 128 + c];
        a2 += cv * Wv[k * 128 + c];
    }
    Tgb[row * 128 + c] = f2b(a1);
    Vgt[((size_t)b * 128 + c) * NP + n] = f2b(a2);
}

// K4a: global scores + fused row softmax -> P bf16 [b][NWIN][NP] (pad zeroed)
__global__ __launch_bounds__(256, 1) void k_qk(
    const unsigned short* __restrict__ Tgb, const unsigned short* __restrict__ ctrb,
    unsigned short* __restrict__ P) {
    extern __shared__ unsigned short Srow[];  // [32][1344] bf16 raw scores
    __shared__ float mxs[32], invs[32];
    int blk = blockIdx.x, b = blockIdx.y;
    int mb = blk * 32;
    int tid = threadIdx.x, wid = tid >> 6, lane = tid & 63;
    int lr = lane & 15, lg = lane >> 4;
    int wm = (wid & 1) * 16, wn = (wid >> 1) * 32;

    const unsigned short* Arow = Tgb + ((size_t)b * NWIN + mb + wm + lr) * 128;
    for (int tile = 0; tile < 21; ++tile) {
        int nb = tile * 64 + wn;
        f32x4 acc[2] = {};
        #pragma unroll
        for (int ks = 0; ks < 4; ++ks) {
            int k = ks * 32 + lg * 8;
            bfrag a = *(const bfrag*)(Arow + k);
            #pragma unroll
            for (int nt = 0; nt < 2; ++nt) {
                bfrag bb = *(const bfrag*)(ctrb + ((size_t)b * NWIN + nb + nt * 16 + lr) * 128 + k);
                acc[nt] = MFMA16(a, bb, acc[nt], 0, 0, 0);
            }
        }
        #pragma unroll
        for (int nt = 0; nt < 2; ++nt) {
            int col = nb + nt * 16 + lr;
            #pragma unroll
            for (int r = 0; r < 4; ++r) {
                int mrow = wm + 4 * lg + r;
                Srow[mrow * 1344 + col] = f2b(acc[nt][r]);
            }
        }
    }
    __syncthreads();
    {   // row max + sum(exp): 8 threads per row
        int row = tid >> 3, sub = tid & 7;
        const unsigned short* sr = Srow + row * 1344;
        float mx = -1e30f;
        for (int c = sub; c < 1344; c += 8) mx = fmaxf(mx, b2f(sr[c]));
        mx = fmaxf(mx, __shfl_xor(mx, 1));
        mx = fmaxf(mx, __shfl_xor(mx, 2));
        mx = fmaxf(mx, __shfl_xor(mx, 4));
        float sum = 0.f;
        for (int c = sub; c < 1344; c += 8) sum += __expf((b2f(sr[c]) - mx) * SCALE);
        sum += __shfl_xor(sum, 1);
        sum += __shfl_xor(sum, 2);
        sum += __shfl_xor(sum, 4);
        if (sub == 0) { mxs[row] = mx; invs[row] = 1.0f / sum; }
    }
    __syncthreads();
    unsigned short* Pb = P + ((size_t)b * NWIN + mb) * NP;
    for (int idx = tid; idx < 32 * (NP / 8); idx += 256) {
        int row = idx / (NP / 8), c8 = idx % (NP / 8);
        float mx = mxs[row], inv = invs[row];
        unsigned short o[8];
        #pragma unroll
        for (int e = 0; e < 8; ++e) {
            int c = c8 * 8 + e;
            float p = (c < 1344) ? __expf((b2f(Srow[row * 1344 + c]) - mx) * SCALE) * inv : 0.f;
            o[e] = f2b(p);
        }
        *(int4*)(Pb + row * NP + c8 * 8) = *(int4*)o;
    }
}

// K4b: Y^T = Vgt x P^T; ycen = Y * centers; FUSED g0 = ycen @ G0 via LDS Y-tile
__global__ __launch_bounds__(256) void k_pvg0(
    const unsigned short* __restrict__ P, const unsigned short* __restrict__ Vgt,
    const float* __restrict__ ctr, const unsigned short* __restrict__ G0tB,
    float* __restrict__ ycen, float* __restrict__ g0g) {
    __shared__ __align__(16) char Ys[32 * 256];  // [32 m][128 c] bf16, swizzled
    int blk = blockIdx.x, b = blockIdx.y;
    int mb = blk * 32;
    int tid = threadIdx.x, wid = tid >> 6, lane = tid & 63;
    int lr = lane & 15, lg = lane >> 4;
    int cb = wid * 32;
    f32x4 acc[2][2] = {};  // [ci][mj]
    const unsigned short* Pb = P + ((size_t)b * NWIN + mb) * NP;
    const unsigned short* Vb = Vgt + (size_t)b * 128 * NP;
    for (int it = 0; it < 44; ++it) {
        int k = it * 32 + lg * 8;
        bfrag a0 = *(const bfrag*)(Vb + (size_t)(cb + lr) * NP + k);
        bfrag a1 = *(const bfrag*)(Vb + (size_t)(cb + 16 + lr) * NP + k);
        bfrag b0 = *(const bfrag*)(Pb + (size_t)lr * NP + k);
        bfrag b1 = *(const bfrag*)(Pb + (size_t)(16 + lr) * NP + k);
        acc[0][0] = MFMA16(a0, b0, acc[0][0], 0, 0, 0);
        acc[0][1] = MFMA16(a0, b1, acc[0][1], 0, 0, 0);
        acc[1][0] = MFMA16(a1, b0, acc[1][0], 0, 0, 0);
        acc[1][1] = MFMA16(a1, b1, acc[1][1], 0, 0, 0);
    }
    #pragma unroll
    for (int ci = 0; ci < 2; ++ci)
        #pragma unroll
        for (int mj = 0; mj < 2; ++mj) {
            int c0 = cb + ci * 16 + 4 * lg;
            int mr = mj * 16 + lr;
            int m = mb + mr;
            size_t base = ((size_t)b * NWIN + m) * 128 + c0;
            float4 cv = *(const float4*)(ctr + base);
            float4 y;
            y.x = acc[ci][mj][0] * cv.x;
            y.y = acc[ci][mj][1] * cv.y;
            y.z = acc[ci][mj][2] * cv.z;
            y.w = acc[ci][mj][3] * cv.w;
            *(float4*)(ycen + base) = y;
            int2 pv; pv.x = pack2(y.x, y.y); pv.y = pack2(y.z, y.w);
            *(int2*)(Ys + mr * 256 + ((2 * c0) ^ ((mr & 7) << 4))) = pv;
        }
    __syncthreads();
    // g0 = Y(32 rows) @ G0 : A = G0t (global, L2-hot), B = Ys rows
    {
        int nb = wid * 32;
        f32x4 g[2][2] = {};  // [ni][mj]
        #pragma unroll
        for (int ks = 0; ks < 4; ++ks) {
            int k = ks * 32 + lg * 8;
            bfrag a0 = *(const bfrag*)(G0tB + (nb + lr) * 128 + k);
            bfrag a1 = *(const bfrag*)(G0tB + (nb + 16 + lr) * 128 + k);
            bfrag b0 = ld256(Ys, lr, k);
            bfrag b1 = ld256(Ys, 16 + lr, k);
            g[0][0] = MFMA16(a0, b0, g[0][0], 0, 0, 0);
            g[0][1] = MFMA16(a0, b1, g[0][1], 0, 0, 0);
            g[1][0] = MFMA16(a1, b0, g[1][0], 0, 0, 0);
            g[1][1] = MFMA16(a1, b1, g[1][1], 0, 0, 0);
        }
        #pragma unroll
        for (int ni = 0; ni < 2; ++ni)
            #pragma unroll
            for (int mj = 0; mj < 2; ++mj) {
                int m = mb + mj * 16 + lr;
                int n0 = nb + ni * 16 + 4 * lg;
                #pragma unroll
                for (int r = 0; r < 4; ++r)
                    g0g[((size_t)b * NWIN + m) * 128 + n0 + r] = g[ni][mj][r];
            }
    }
}

// ---------- K5: fused local window attention via MFMA (80 KB, 2 blocks/CU) ----
// Round-10 structure: 5 barriers, P stored inside XM row t (wave-private).
#define XB_OFF 0
#define WT_OFF 16384
#define XM_OFF 49152
#define VT_OFF 65536
#define SMEM_SZ 81920

__global__ __launch_bounds__(256, 2) void k_local_mfma(
    const float* __restrict__ f0, const float* __restrict__ f1,
    const float* __restrict__ f2,
    const unsigned short* __restrict__ MtB,
    const unsigned short* __restrict__ WvltB,
    const unsigned short* __restrict__ G1tB,
    const float* __restrict__ g0g, const float* __restrict__ ycen,
    float* __restrict__ out) {
    extern __shared__ char smem[];
    char* Xb = smem + XB_OFF;    // X; yl in-place during phase 4
    char* Wt = smem + WT_OFF;    // Mt -> Wvlt -> G1t
    char* XMb = smem + XM_OFF;   // XM; P lives in row t's first 128 B (wave-private)
    char* Vt = smem + VT_OFF;

    int w = blockIdx.x, b = blockIdx.y;
    const float* f; int p0, HW, obase;
    window_src(w * WT, f0, f1, f2, f, p0, HW, obase);

    int tid = threadIdx.x;
    int wid = tid >> 6, lane = tid & 63;
    int lr = lane & 15, lg = lane >> 4;

    // ---- phase 0: stage X (f32->bf16 swizzled) + Mt weights ----
    {
        int t0 = tid & 63, cq = tid >> 6;
        const float* src = f + (size_t)(b * 128 + cq * 32) * HW + p0 + t0;
        float xv[32];
        #pragma unroll
        for (int i = 0; i < 32; ++i) xv[i] = src[(size_t)i * HW];
        int4 wreg[8];
        const int4* wsrc = (const int4*)MtB;
        #pragma unroll
        for (int j = 0; j < 8; ++j) wreg[j] = wsrc[j * 256 + tid];
        #pragma unroll
        for (int j = 0; j < 4; ++j) {
            int c0 = cq * 32 + j * 8;
            int4 v;
            v.x = pack2(xv[j * 8 + 0], xv[j * 8 + 1]);
            v.y = pack2(xv[j * 8 + 2], xv[j * 8 + 3]);
            v.z = pack2(xv[j * 8 + 4], xv[j * 8 + 5]);
            v.w = pack2(xv[j * 8 + 6], xv[j * 8 + 7]);
            *(int4*)(Xb + t0 * 256 + ((2 * c0) ^ ((t0 & 7) << 4))) = v;
        }
        #pragma unroll
        for (int j = 0; j < 8; ++j) {
            int ci = j * 256 + tid, n = ci >> 4, pos = ci & 15;
            *(int4*)(Wt + n * 256 + ((pos * 16) ^ ((n & 7) << 4))) = wreg[j];
        }
    }
    __syncthreads();  // B1

    int t = 16 * wid + lr;

    // ---- phase 1: XM^T = Mt(A,LDS) x X(B) -> XMb (wave-private rows) ----
    {
        f32x4 acc[8] = {};
        #pragma unroll
        for (int ks = 0; ks < 4; ++ks) {
            int k = ks * 32 + lg * 8;
            bfrag xb = ld256(Xb, t, k);
            #pragma unroll
            for (int ct = 0; ct < 8; ++ct) {
                bfrag am = ld256(Wt, 16 * ct + lr, k);
                acc[ct] = MFMA16(am, xb, acc[ct], 0, 0, 0);
            }
        }
        #pragma unroll
        for (int ct = 0; ct < 8; ++ct) {
            int c0 = 16 * ct + 4 * lg;
            int2 v; v.x = pack2(acc[ct][0], acc[ct][1]); v.y = pack2(acc[ct][2], acc[ct][3]);
            *(int2*)(XMb + t * 256 + ((2 * c0) ^ ((t & 7) << 4))) = v;
        }
    }
    __syncthreads();  // B2 (Mt reads done everywhere; XM rows are wave-private)

    // ---- phase 2: S^T + softmax; P overwrites own XM row (no barrier); Wvlt ----
    {
        int4 wreg[8];
        const int4* wsrc = (const int4*)WvltB;
        #pragma unroll
        for (int j = 0; j < 8; ++j) wreg[j] = wsrc[j * 256 + tid];

        f32x4 s[4] = {};
        #pragma unroll
        for (int ks = 0; ks < 4; ++ks) {
            int k = ks * 32 + lg * 8;
            bfrag bxm = ld256(XMb, t, k);
            #pragma unroll
            for (int ut = 0; ut < 4; ++ut) {
                bfrag ax = ld256(Xb, 16 * ut + lr, k);
                s[ut] = MFMA16(ax, bxm, s[ut], 0, 0, 0);
            }
        }
        float m = -1e30f;
        #pragma unroll
        for (int ut = 0; ut < 4; ++ut)
            #pragma unroll
            for (int r = 0; r < 4; ++r) m = fmaxf(m, s[ut][r]);
        m = fmaxf(m, __shfl_xor(m, 16));
        m = fmaxf(m, __shfl_xor(m, 32));
        float sum = 0.f;
        float e[4][4];
        #pragma unroll
        for (int ut = 0; ut < 4; ++ut)
            #pragma unroll
            for (int r = 0; r < 4; ++r) {
                e[ut][r] = __expf((s[ut][r] - m) * SCALE);
                sum += e[ut][r];
            }
        sum += __shfl_xor(sum, 16);
        sum += __shfl_xor(sum, 32);
        float pinv = 1.0f / sum;
        // P write into OWN XM row t (wave-private) — no block barrier needed.
        #pragma unroll
        for (int ut = 0; ut < 4; ++ut) {
            int u0 = 16 * ut + 4 * lg;
            int2 v;
            v.x = pack2(e[ut][0] * pinv, e[ut][1] * pinv);
            v.y = pack2(e[ut][2] * pinv, e[ut][3] * pinv);
            *(int2*)(XMb + t * 256 + ((2 * u0) ^ ((t & 7) << 4))) = v;
        }
        #pragma unroll
        for (int j = 0; j < 8; ++j) {
            int ci = j * 256 + tid, n = ci >> 4, pos = ci & 15;
            *(int4*)(Wt + n * 256 + ((pos * 16) ^ ((n & 7) << 4))) = wreg[j];
        }
    }
    __syncthreads();  // B3 (Wvlt visible)

    // ---- phase 3: V^T = X(A) x Wvlt(B,LDS) -> Vt; issue G1t loads ----
    int4 wregG[8];
    {
        const int4* wsrc = (const int4*)G1tB;
        #pragma unroll
        for (int j = 0; j < 8; ++j) wregG[j] = wsrc[j * 256 + tid];

        f32x4 vacc[8] = {};
        #pragma unroll
        for (int ks = 0; ks < 4; ++ks) {
            int k = ks * 32 + lg * 8;
            bfrag ax = ld256(Xb, t, k);
            #pragma unroll
            for (int ct = 0; ct < 8; ++ct) {
                bfrag bw = ld256(Wt, 16 * ct + lr, k);
                vacc[ct] = MFMA16(ax, bw, vacc[ct], 0, 0, 0);
            }
        }
        #pragma unroll
        for (int ct = 0; ct < 8; ++ct) {
            int c = 16 * ct + lr;
            int u0 = 16 * wid + 4 * lg;
            int2 v; v.x = pack2(vacc[ct][0], vacc[ct][1]); v.y = pack2(vacc[ct][2], vacc[ct][3]);
            *(int2*)(Vt + c * 128 + ((2 * u0) ^ ((c & 7) << 4))) = v;
        }
    }
    __syncthreads();  // B4 (Wvlt reads done; Vt visible)

    // ---- phase 4: stage G1t; Y^T = Vt(A) x P(B); yl = Y*X in-place; yg/g0 ----
    float yl[8][4];
    float4 yg4[8], g04[8];
    {
        #pragma unroll
        for (int j = 0; j < 8; ++j) {
            int ci = j * 256 + tid, n = ci >> 4, pos = ci & 15;
            *(int4*)(Wt + n * 256 + ((pos * 16) ^ ((n & 7) << 4))) = wregG[j];
        }
        size_t rbase = ((size_t)b * NWIN + w) * 128 + 4 * lg;
        #pragma unroll
        for (int nt = 0; nt < 8; ++nt) {
            yg4[nt] = *(const float4*)(ycen + rbase + 16 * nt);
            g04[nt] = *(const float4*)(g0g + rbase + 16 * nt);
        }
        f32x4 y[8] = {};
        #pragma unroll
        for (int us = 0; us < 2; ++us) {
            int u = us * 32 + lg * 8;
            bfrag bp = ld256(XMb, t, u);  // P (stride-256, own row)
            #pragma unroll
            for (int ct = 0; ct < 8; ++ct) {
                bfrag av = ld128(Vt, 16 * ct + lr, u);
                y[ct] = MFMA16(av, bp, y[ct], 0, 0, 0);
            }
        }
        #pragma unroll
        for (int ct = 0; ct < 8; ++ct) {
            int c0 = 16 * ct + 4 * lg;
            int2 xw = *(const int2*)(Xb + t * 256 + ((2 * c0) ^ ((t & 7) << 4)));
            float x0 = b2f((unsigned short)(xw.x & 0xffff));
            float x1 = b2f((unsigned short)((unsigned)xw.x >> 16));
            float x2 = b2f((unsigned short)(xw.y & 0xffff));
            float x3 = b2f((unsigned short)((unsigned)xw.y >> 16));
            yl[ct][0] = y[ct][0] * x0;
            yl[ct][1] = y[ct][1] * x1;
            yl[ct][2] = y[ct][2] * x2;
            yl[ct][3] = y[ct][3] * x3;
            int2 v; v.x = pack2(yl[ct][0], yl[ct][1]); v.y = pack2(yl[ct][2], yl[ct][3]);
            *(int2*)(Xb + t * 256 + ((2 * c0) ^ ((t & 7) << 4))) = v;  // in-place yl
        }
    }
    __syncthreads();  // B5 (G1t + yl visible)

    // ---- phase 5: G^T = G1t(A,LDS) x yl(B); alpha; blend + store ----
    {
        f32x4 g[8] = {};
        #pragma unroll
        for (int ks = 0; ks < 4; ++ks) {
            int k = ks * 32 + lg * 8;
            bfrag byl = ld256(Xb, t, k);  // yl
            #pragma unroll
            for (int nt = 0; nt < 8; ++nt) {
                bfrag ag = ld256(Wt, 16 * nt + lr, k);
                g[nt] = MFMA16(ag, byl, g[nt], 0, 0, 0);
            }
        }
        #pragma unroll
        for (int nt = 0; nt < 8; ++nt) {
            float gv[4] = {g04[nt].x, g04[nt].y, g04[nt].z, g04[nt].w};
            float yv4[4] = {yg4[nt].x, yg4[nt].y, yg4[nt].z, yg4[nt].w};
            #pragma unroll
            for (int r = 0; r < 4; ++r) {
                int c = 16 * nt + 4 * lg + r;
                float a = 1.0f / (1.0f + __expf(-(g[nt][r] + gv[r])));
                float yv = a * yv4[r] + (1.0f - a) * yl[nt][r];
                out[obase + (size_t)(b * 128 + c) * HW + p0 + t] = yv;
            }
        }
    }
}

// ---------- K6/K7 v4: conv3x3 + PixelShuffle + residual, MFMA fp16 ----------
// Weights never touch LDS: register double-buffered direct-L2 A-fragments.
template <int H, int W>
__global__ __launch_bounds__(256, 2) void k_conv_mfma(
    const float* __restrict__ in, const _Float16* __restrict__ Wcv,
    float* __restrict__ out) {
    constexpr int TXN = W / 32;
    int tile = blockIdx.x;
    int ty = tile / TXN, tx = tile % TXN;
    int y0 = ty * 4, x0 = tx * 32;
    int ob = blockIdx.y * 256;
    int b = blockIdx.z;

    __shared__ __align__(16) char sXs[16384];  // 204 rows x 80B, slot swz (row>>3)&1

    int tid = threadIdx.x;
    int wid = tid >> 6, lane = tid & 63;
    int lr = lane & 15, lg = lane >> 4;

    f32x4 acc[8][4] = {};

    int sy = tid / 34, sx = tid - sy * 34;
    int gy = y0 + sy - 1, gx = x0 + sx - 1;
    bool act = tid < 204;
    bool ok = act && gy >= 0 && gy < H && gx >= 0 && gx < W;
    const float* gp = in + (size_t)b * 128 * H * W + (size_t)gy * W + gx;
    int xswz = (tid >> 3) & 1;

    const _Float16* wbase = Wcv + (size_t)(ob + lr) * 32 + lg * 8;

    hfrag afC[4], afN[4];
    #pragma unroll
    for (int n = 0; n < 4; ++n)
        afC[n] = *(const hfrag*)(wbase + (size_t)(wid * 4 + n) * 512);

    if (act) {
        float xv[32];
        if (ok) {
            #pragma unroll
            for (int ic = 0; ic < 32; ++ic) xv[ic] = gp[(size_t)ic * H * W];
        } else {
            #pragma unroll
            for (int ic = 0; ic < 32; ++ic) xv[ic] = 0.f;
        }
        #pragma unroll
        for (int s = 0; s < 4; ++s) {
            _Float16 hh[8];
            #pragma unroll
            for (int e = 0; e < 8; ++e) hh[e] = (_Float16)xv[s * 8 + e];
            *(int4*)(sXs + tid * 80 + ((s ^ xswz) << 4)) = *(int4*)hh;
        }
    }
    __syncthreads();

    for (int ics = 0; ics < 4; ++ics) {
        if (ics) {
            __syncthreads();
            if (act) {
                float xv[32];
                if (ok) {
                    #pragma unroll
                    for (int ic = 0; ic < 32; ++ic)
                        xv[ic] = gp[(size_t)(ics * 32 + ic) * H * W];
                } else {
                    #pragma unroll
                    for (int ic = 0; ic < 32; ++ic) xv[ic] = 0.f;
                }
                #pragma unroll
                for (int s = 0; s < 4; ++s) {
                    _Float16 hh[8];
                    #pragma unroll
                    for (int e = 0; e < 8; ++e) hh[e] = (_Float16)xv[s * 8 + e];
                    *(int4*)(sXs + tid * 80 + ((s ^ xswz) << 4)) = *(int4*)hh;
                }
            }
            __syncthreads();
        }
        #pragma unroll
        for (int tap = 0; tap < 9; ++tap) {
            int kg = ics * 9 + tap;
            if (tap < 8 || ics < 3) {
                const _Float16* ws = wbase + (size_t)(kg + 1) * 16384;
                #pragma unroll
                for (int n = 0; n < 4; ++n)
                    afN[n] = *(const hfrag*)(ws + (size_t)(wid * 4 + n) * 512);
            }
            int dy = tap / 3, dx = tap - dy * 3;
            hfrag bf[8];
            #pragma unroll
            for (int m = 0; m < 8; ++m) {
                int row = ((m >> 1) + dy) * 34 + (m & 1) * 16 + lr + dx;
                bf[m] = *(const hfrag*)(sXs + row * 80 + ((lg ^ ((row >> 3) & 1)) << 4));
            }
            #pragma unroll
            for (int m = 0; m < 8; ++m)
                #pragma unroll
                for (int n = 0; n < 4; ++n)
                    acc[m][n] = MFMA16H(afC[n], bf[m], acc[m][n], 0, 0, 0);
            #pragma unroll
            for (int n = 0; n < 4; ++n) afC[n] = afN[n];
        }
    }

    float* outb = out + (size_t)b * 128 * 4 * H * W;
    #pragma unroll
    for (int n = 0; n < 4; ++n) {
        int oc0 = ob + (wid * 4 + n) * 16 + lg * 4;
        int c = oc0 >> 2;
        #pragma unroll
        for (int mr = 0; mr < 4; ++mr) {
            int py = y0 + mr;
            #pragma unroll
            for (int i2 = 0; i2 < 2; ++i2) {
                size_t rowb = ((size_t)c * (2 * H) + 2 * py + i2) * (2 * W);
                float2* p0 = (float2*)(outb + rowb + 2 * (x0 + lr));
                float2 v0 = *p0;
                v0.x += acc[2 * mr][n][i2 * 2 + 0];
                v0.y += acc[2 * mr][n][i2 * 2 + 1];
                *p0 = v0;
                float2* p1 = (float2*)(outb + rowb + 2 * (x0 + 16 + lr));
                float2 v1 = *p1;
                v1.x += acc[2 * mr + 1][n][i2 * 2 + 0];
                v1.y += acc[2 * mr + 1][n][i2 * 2 + 1];
                *p1 = v1;
            }
        }
    }
}

extern "C" void kernel_launch(void* const* d_in, const int* in_sizes, int n_in,
                              void* d_out, int out_size, void* d_ws, size_t ws_size,
                              hipStream_t stream) {
    const float* f0 = (const float*)d_in[0];
    const float* f1 = (const float*)d_in[1];
    const float* f2 = (const float*)d_in[2];
    const float* Wq = (const float*)d_in[3];
    const float* Wk = (const float*)d_in[4];
    const float* Wv = (const float*)d_in[5];
    const float* Wql = (const float*)d_in[6];
    const float* Wkl = (const float*)d_in[7];
    const float* Wvl = (const float*)d_in[8];
    const float* gate_w = (const float*)d_in[9];
    const float* conv0 = (const float*)d_in[10];
    const float* conv1 = (const float*)d_in[11];
    float* out = (float*)d_out;
    float* ws = (float*)d_ws;

    float* Mglob = ws;                    // 16384 f32
    float* ctr = Mglob + 16384;           // 688128 f32
    float* ycen = ctr + 688128;           // 688128 f32
    float* g0g = ycen + 688128;           // 688128 f32
    unsigned short* MtB = (unsigned short*)(g0g + 688128);   // 16384 bf16
    unsigned short* WvltB = MtB + 16384;                     // 16384 bf16
    unsigned short* G1tB = WvltB + 16384;                    // 16384 bf16
    unsigned short* G0tB = G1tB + 16384;                     // 16384 bf16
    _Float16* Wcv0 = (_Float16*)(G0tB + 16384);              // 589824 f16
    _Float16* Wcv1 = Wcv0 + 589824;                          // 589824 f16
    unsigned short* ctrb = (unsigned short*)(Wcv1 + 589824); // 688128 bf16
    unsigned short* Tgb = ctrb + 688128;                     // 688128 bf16
    unsigned short* Vgt = Tgb + 688128;                      // 4*128*NP bf16
    unsigned short* Pg = Vgt + 4 * 128 * NP;                 // 4*NWIN*NP bf16

    hipFuncSetAttribute((const void*)k_local_mfma,
                        hipFuncAttributeMaxDynamicSharedMemorySize, SMEM_SZ);
    hipFuncSetAttribute((const void*)k_qk,
                        hipFuncAttributeMaxDynamicSharedMemorySize, 32 * 1344 * 2);

    k_mm<<<dim3(128), 128, 0, stream>>>(Wq, Wk, Mglob);
    k_prep<<<dim3(128, 4), 128, 0, stream>>>(Wql, Wkl, Wvl, gate_w, MtB, WvltB, G1tB, G0tB);
    k_prep_conv<<<dim3(2304, 2), 256, 0, stream>>>(conv0, conv1, Wcv0, Wcv1);
    k_centers<<<dim3(NWIN, 4), 256, 0, stream>>>(f0, f1, f2, ctr, ctrb);
    k_tgvg<<<dim3(NWIN, 4), 128, 0, stream>>>(ctr, Mglob, Wv, Tgb, Vgt);
    k_qk<<<dim3(NWIN / 32, 4), 256, 32 * 1344 * 2, stream>>>(Tgb, ctrb, Pg);
    k_pvg0<<<dim3(NWIN / 32, 4), 256, 0, stream>>>(Pg, Vgt, ctr, G0tB, ycen, g0g);
    k_local_mfma<<<dim3(NWIN, 4), 256, SMEM_SZ, stream>>>(
        f0, f1, f2, MtB, WvltB, G1tB, g0g, ycen, out);
    k_conv_mfma<64, 64><<<dim3(32, 2, 4), 256, 0, stream>>>(out + OUT0, Wcv0, out + OUT1);
    k_conv_mfma<128, 128><<<dim3(128, 2, 4), 256, 0, stream>>>(out + OUT1, Wcv1, out + OUT2);
}

// Round 14
// 568.711 us; speedup vs baseline: 1.1160x; 1.0467x over previous
//
#include <hip/hip_runtime.h>
#include <math.h>

#define WT 64
#define NWIN 1344
#define NP 1408  // padded key dim for PV GEMM
constexpr float SCALE = 0.088388347648318447f;  // 128^-0.5

// out region offsets (floats)
#define OUT0 0
#define OUT1 2097152
#define OUT2 10485760

typedef __attribute__((ext_vector_type(8))) short bfrag;      // 8 bf16
typedef __attribute__((ext_vector_type(8))) _Float16 hfrag;   // 8 fp16
typedef __attribute__((ext_vector_type(4))) float f32x4;      // MFMA C/D

#define MFMA16 __builtin_amdgcn_mfma_f32_16x16x32_bf16
#define MFMA16H __builtin_amdgcn_mfma_f32_16x16x32_f16

__device__ __forceinline__ unsigned short f2b(float f) {
    union { float f; unsigned u; } v; v.f = f;
    unsigned r = v.u + 0x7fffu + ((v.u >> 16) & 1u);  // rne
    return (unsigned short)(r >> 16);
}
__device__ __forceinline__ float b2f(unsigned short u) {
    union { unsigned u; float f; } v; v.u = ((unsigned)u) << 16; return v.f;
}
__device__ __forceinline__ int pack2(float a, float b) {
    return (int)f2b(a) | ((int)f2b(b) << 16);
}

// swizzled LDS fragment loads: row-major bf16 tiles, byte ^= (row&7)<<4
__device__ __forceinline__ bfrag ld256(const char* region, int row, int k) {
    int off = (2 * k) ^ ((row & 7) << 4);
    return *(const bfrag*)(region + row * 256 + off);
}
__device__ __forceinline__ bfrag ld128(const char* region, int row, int k) {
    int off = (2 * k) ^ ((row & 7) << 4);
    return *(const bfrag*)(region + row * 128 + off);
}

// K1b: bf16 transposed weight prep (+ gate G0, + global-path Mgt/Wvt).
__global__ void k_prep(const float* __restrict__ Wql, const float* __restrict__ Wkl,
                       const float* __restrict__ Wvl, const float* __restrict__ gw,
                       const float* __restrict__ Wq, const float* __restrict__ Wk,
                       const float* __restrict__ Wv,
                       unsigned short* __restrict__ MtB,
                       unsigned short* __restrict__ WvltB,
                       unsigned short* __restrict__ G1tB,
                       unsigned short* __restrict__ G0tB,
                       unsigned short* __restrict__ MgtB,
                       unsigned short* __restrict__ WvtB) {
    int n = blockIdx.x, k = threadIdx.x;
    if (blockIdx.y == 0) {
        float a = 0.f;
        for (int c = 0; c < 128; ++c) a += Wkl[n * 128 + c] * Wql[k * 128 + c];
        MtB[n * 128 + k] = f2b(a);
    } else if (blockIdx.y == 1) {
        WvltB[n * 128 + k] = f2b(Wvl[k * 128 + n]);
    } else if (blockIdx.y == 2) {
        G1tB[n * 128 + k] = f2b(gw[(128 + k) * 128 + n]);
    } else if (blockIdx.y == 3) {
        G0tB[n * 128 + k] = f2b(gw[k * 128 + n]);
    } else if (blockIdx.y == 4) {
        // Mgt[n][k] = Mglob[k][n] = Wq_row_k . Wk_row_n
        float a = 0.f;
        for (int c = 0; c < 128; ++c) a += Wk[n * 128 + c] * Wq[k * 128 + c];
        MgtB[n * 128 + k] = f2b(a);
    } else {
        WvtB[n * 128 + k] = f2b(Wv[k * 128 + n]);
    }
}

// K1c: conv weight prep -> fp16 image [36 slices][512 oc][32 k]
__global__ __launch_bounds__(256) void k_prep_conv(
    const float* __restrict__ w0, const float* __restrict__ w1,
    _Float16* __restrict__ W0, _Float16* __restrict__ W1) {
    int idx = blockIdx.x * 256 + threadIdx.x;  // < 589824 = 36*512*32
    const float* w = blockIdx.y ? w1 : w0;
    _Float16* o = blockIdx.y ? W1 : W0;
    int slice = idx >> 14, rem = idx & 16383;
    int oc = rem >> 5, k = rem & 31;
    int ics = slice / 9, tap = slice - ics * 9;
    o[idx] = (_Float16)w[((size_t)oc * 128 + ics * 32 + k) * 9 + tap];
}

__device__ __forceinline__ void window_src(int n0, const float* f0, const float* f1,
                                           const float* f2, const float*& f, int& p0,
                                           int& HW, int& obase) {
    if (n0 < 4096)        { f = f0; p0 = n0;          HW = 4096;  obase = OUT0; }
    else if (n0 < 20480)  { f = f1; p0 = n0 - 4096;   HW = 16384; obase = OUT1; }
    else                  { f = f2; p0 = n0 - 20480;  HW = 65536; obase = OUT2; }
}

// K2: window means -> centers f32 [B,NWIN,128] + bf16 copy
__global__ __launch_bounds__(256) void k_centers(
    const float* __restrict__ f0, const float* __restrict__ f1,
    const float* __restrict__ f2, float* __restrict__ ctr,
    unsigned short* __restrict__ ctrb) {
    int w = blockIdx.x, b = blockIdx.y;
    const float* f; int p0, HW, ob;
    window_src(w * WT, f0, f1, f2, f, p0, HW, ob);
    int lane = threadIdx.x & 63, cg = threadIdx.x >> 6;
    for (int c = cg; c < 128; c += 4) {
        float v = f[(b * 128 + c) * HW + p0 + lane];
        #pragma unroll
        for (int off = 32; off; off >>= 1) v += __shfl_xor(v, off);
        if (lane == 0) {
            float mv = v * (1.0f / 64.0f);
            ctr[(b * NWIN + w) * 128 + c] = mv;
            ctrb[(b * NWIN + w) * 128 + c] = f2b(mv);
        }
    }
}

// K3 v2: MFMA GEMMs  Tg = ctr @ Mglob (row-major out), Vg^T (transposed out).
// A-frags direct from L2-hot MgtB/WvtB; B-frags from ctrb rows.
__global__ __launch_bounds__(256) void k_tgvg2(
    const unsigned short* __restrict__ ctrb, const unsigned short* __restrict__ MgtB,
    const unsigned short* __restrict__ WvtB, unsigned short* __restrict__ Tgb,
    unsigned short* __restrict__ Vgt) {
    int blk = blockIdx.x, b = blockIdx.y;
    int mb = blk * 32;
    int tid = threadIdx.x, wid = tid >> 6, lane = tid & 63;
    int lr = lane & 15, lg = lane >> 4;
    int nb = wid * 32;
    f32x4 tg[2][2] = {};  // [ni][mj]
    f32x4 vg[2][2] = {};
    const unsigned short* Cb = ctrb + ((size_t)b * NWIN + mb) * 128;
    #pragma unroll
    for (int ks = 0; ks < 4; ++ks) {
        int k = ks * 32 + lg * 8;
        bfrag b0 = *(const bfrag*)(Cb + lr * 128 + k);
        bfrag b1 = *(const bfrag*)(Cb + (16 + lr) * 128 + k);
        bfrag m0 = *(const bfrag*)(MgtB + (nb + lr) * 128 + k);
        bfrag m1 = *(const bfrag*)(MgtB + (nb + 16 + lr) * 128 + k);
        bfrag v0 = *(const bfrag*)(WvtB + (nb + lr) * 128 + k);
        bfrag v1 = *(const bfrag*)(WvtB + (nb + 16 + lr) * 128 + k);
        tg[0][0] = MFMA16(m0, b0, tg[0][0], 0, 0, 0);
        tg[0][1] = MFMA16(m0, b1, tg[0][1], 0, 0, 0);
        tg[1][0] = MFMA16(m1, b0, tg[1][0], 0, 0, 0);
        tg[1][1] = MFMA16(m1, b1, tg[1][1], 0, 0, 0);
        vg[0][0] = MFMA16(v0, b0, vg[0][0], 0, 0, 0);
        vg[0][1] = MFMA16(v0, b1, vg[0][1], 0, 0, 0);
        vg[1][0] = MFMA16(v1, b0, vg[1][0], 0, 0, 0);
        vg[1][1] = MFMA16(v1, b1, vg[1][1], 0, 0, 0);
    }
    #pragma unroll
    for (int ni = 0; ni < 2; ++ni)
        #pragma unroll
        for (int mj = 0; mj < 2; ++mj) {
            int n0 = nb + ni * 16 + 4 * lg;
            int m = mb + mj * 16 + lr;
            // Tgb row-major [m][128]
            int2 tv;
            tv.x = pack2(tg[ni][mj][0], tg[ni][mj][1]);
            tv.y = pack2(tg[ni][mj][2], tg[ni][mj][3]);
            *(int2*)(Tgb + ((size_t)b * NWIN + m) * 128 + n0) = tv;
            // Vgt transposed [c][NP]
            #pragma unroll
            for (int r = 0; r < 4; ++r)
                Vgt[((size_t)b * 128 + n0 + r) * NP + m] = f2b(vg[ni][mj][r]);
        }
}

// K4a: global scores + fused row softmax -> P bf16 [b][NWIN][NP] (pad zeroed)
__global__ __launch_bounds__(256, 1) void k_qk(
    const unsigned short* __restrict__ Tgb, const unsigned short* __restrict__ ctrb,
    unsigned short* __restrict__ P) {
    extern __shared__ unsigned short Srow[];  // [32][1344] bf16 raw scores
    __shared__ float mxs[32], invs[32];
    int blk = blockIdx.x, b = blockIdx.y;
    int mb = blk * 32;
    int tid = threadIdx.x, wid = tid >> 6, lane = tid & 63;
    int lr = lane & 15, lg = lane >> 4;
    int wm = (wid & 1) * 16, wn = (wid >> 1) * 32;

    const unsigned short* Arow = Tgb + ((size_t)b * NWIN + mb + wm + lr) * 128;
    for (int tile = 0; tile < 21; ++tile) {
        int nb = tile * 64 + wn;
        f32x4 acc[2] = {};
        #pragma unroll
        for (int ks = 0; ks < 4; ++ks) {
            int k = ks * 32 + lg * 8;
            bfrag a = *(const bfrag*)(Arow + k);
            #pragma unroll
            for (int nt = 0; nt < 2; ++nt) {
                bfrag bb = *(const bfrag*)(ctrb + ((size_t)b * NWIN + nb + nt * 16 + lr) * 128 + k);
                acc[nt] = MFMA16(a, bb, acc[nt], 0, 0, 0);
            }
        }
        #pragma unroll
        for (int nt = 0; nt < 2; ++nt) {
            int col = nb + nt * 16 + lr;
            #pragma unroll
            for (int r = 0; r < 4; ++r) {
                int mrow = wm + 4 * lg + r;
                Srow[mrow * 1344 + col] = f2b(acc[nt][r]);
            }
        }
    }
    __syncthreads();
    {   // row max + sum(exp): 8 threads per row
        int row = tid >> 3, sub = tid & 7;
        const unsigned short* sr = Srow + row * 1344;
        float mx = -1e30f;
        for (int c = sub; c < 1344; c += 8) mx = fmaxf(mx, b2f(sr[c]));
        mx = fmaxf(mx, __shfl_xor(mx, 1));
        mx = fmaxf(mx, __shfl_xor(mx, 2));
        mx = fmaxf(mx, __shfl_xor(mx, 4));
        float sum = 0.f;
        for (int c = sub; c < 1344; c += 8) sum += __expf((b2f(sr[c]) - mx) * SCALE);
        sum += __shfl_xor(sum, 1);
        sum += __shfl_xor(sum, 2);
        sum += __shfl_xor(sum, 4);
        if (sub == 0) { mxs[row] = mx; invs[row] = 1.0f / sum; }
    }
    __syncthreads();
    unsigned short* Pb = P + ((size_t)b * NWIN + mb) * NP;
    for (int idx = tid; idx < 32 * (NP / 8); idx += 256) {
        int row = idx / (NP / 8), c8 = idx % (NP / 8);
        float mx = mxs[row], inv = invs[row];
        unsigned short o[8];
        #pragma unroll
        for (int e = 0; e < 8; ++e) {
            int c = c8 * 8 + e;
            float p = (c < 1344) ? __expf((b2f(Srow[row * 1344 + c]) - mx) * SCALE) * inv : 0.f;
            o[e] = f2b(p);
        }
        *(int4*)(Pb + row * NP + c8 * 8) = *(int4*)o;
    }
}

// K4b: Y^T = Vgt x P^T; ycen = Y * centers; FUSED g0 = ycen @ G0 via LDS Y-tile
__global__ __launch_bounds__(256) void k_pvg0(
    const unsigned short* __restrict__ P, const unsigned short* __restrict__ Vgt,
    const float* __restrict__ ctr, const unsigned short* __restrict__ G0tB,
    float* __restrict__ ycen, float* __restrict__ g0g) {
    __shared__ __align__(16) char Ys[32 * 256];  // [32 m][128 c] bf16, swizzled
    int blk = blockIdx.x, b = blockIdx.y;
    int mb = blk * 32;
    int tid = threadIdx.x, wid = tid >> 6, lane = tid & 63;
    int lr = lane & 15, lg = lane >> 4;
    int cb = wid * 32;
    f32x4 acc[2][2] = {};  // [ci][mj]
    const unsigned short* Pb = P + ((size_t)b * NWIN + mb) * NP;
    const unsigned short* Vb = Vgt + (size_t)b * 128 * NP;
    for (int it = 0; it < 44; ++it) {
        int k = it * 32 + lg * 8;
        bfrag a0 = *(const bfrag*)(Vb + (size_t)(cb + lr) * NP + k);
        bfrag a1 = *(const bfrag*)(Vb + (size_t)(cb + 16 + lr) * NP + k);
        bfrag b0 = *(const bfrag*)(Pb + (size_t)lr * NP + k);
        bfrag b1 = *(const bfrag*)(Pb + (size_t)(16 + lr) * NP + k);
        acc[0][0] = MFMA16(a0, b0, acc[0][0], 0, 0, 0);
        acc[0][1] = MFMA16(a0, b1, acc[0][1], 0, 0, 0);
        acc[1][0] = MFMA16(a1, b0, acc[1][0], 0, 0, 0);
        acc[1][1] = MFMA16(a1, b1, acc[1][1], 0, 0, 0);
    }
    #pragma unroll
    for (int ci = 0; ci < 2; ++ci)
        #pragma unroll
        for (int mj = 0; mj < 2; ++mj) {
            int c0 = cb + ci * 16 + 4 * lg;
            int mr = mj * 16 + lr;
            int m = mb + mr;
            size_t base = ((size_t)b * NWIN + m) * 128 + c0;
            float4 cv = *(const float4*)(ctr + base);
            float4 y;
            y.x = acc[ci][mj][0] * cv.x;
            y.y = acc[ci][mj][1] * cv.y;
            y.z = acc[ci][mj][2] * cv.z;
            y.w = acc[ci][mj][3] * cv.w;
            *(float4*)(ycen + base) = y;
            int2 pv; pv.x = pack2(y.x, y.y); pv.y = pack2(y.z, y.w);
            *(int2*)(Ys + mr * 256 + ((2 * c0) ^ ((mr & 7) << 4))) = pv;
        }
    __syncthreads();
    // g0 = Y(32 rows) @ G0 : A = G0t (global, L2-hot), B = Ys rows
    {
        int nb = wid * 32;
        f32x4 g[2][2] = {};  // [ni][mj]
        #pragma unroll
        for (int ks = 0; ks < 4; ++ks) {
            int k = ks * 32 + lg * 8;
            bfrag a0 = *(const bfrag*)(G0tB + (nb + lr) * 128 + k);
            bfrag a1 = *(const bfrag*)(G0tB + (nb + 16 + lr) * 128 + k);
            bfrag b0 = ld256(Ys, lr, k);
            bfrag b1 = ld256(Ys, 16 + lr, k);
            g[0][0] = MFMA16(a0, b0, g[0][0], 0, 0, 0);
            g[0][1] = MFMA16(a0, b1, g[0][1], 0, 0, 0);
            g[1][0] = MFMA16(a1, b0, g[1][0], 0, 0, 0);
            g[1][1] = MFMA16(a1, b1, g[1][1], 0, 0, 0);
        }
        #pragma unroll
        for (int ni = 0; ni < 2; ++ni)
            #pragma unroll
            for (int mj = 0; mj < 2; ++mj) {
                int m = mb + mj * 16 + lr;
                int n0 = nb + ni * 16 + 4 * lg;
                #pragma unroll
                for (int r = 0; r < 4; ++r)
                    g0g[((size_t)b * NWIN + m) * 128 + n0 + r] = g[ni][mj][r];
            }
    }
}

// ---------- K5: fused local window attention via MFMA (80 KB, 2 blocks/CU) ----
// Round-10 structure: 5 barriers, P stored inside XM row t (wave-private).
#define XB_OFF 0
#define WT_OFF 16384
#define XM_OFF 49152
#define VT_OFF 65536
#define SMEM_SZ 81920

__global__ __launch_bounds__(256, 2) void k_local_mfma(
    const float* __restrict__ f0, const float* __restrict__ f1,
    const float* __restrict__ f2,
    const unsigned short* __restrict__ MtB,
    const unsigned short* __restrict__ WvltB,
    const unsigned short* __restrict__ G1tB,
    const float* __restrict__ g0g, const float* __restrict__ ycen,
    float* __restrict__ out) {
    extern __shared__ char smem[];
    char* Xb = smem + XB_OFF;    // X; yl in-place during phase 4
    char* Wt = smem + WT_OFF;    // Mt -> Wvlt -> G1t
    char* XMb = smem + XM_OFF;   // XM; P lives in row t's first 128 B (wave-private)
    char* Vt = smem + VT_OFF;

    int w = blockIdx.x, b = blockIdx.y;
    const float* f; int p0, HW, obase;
    window_src(w * WT, f0, f1, f2, f, p0, HW, obase);

    int tid = threadIdx.x;
    int wid = tid >> 6, lane = tid & 63;
    int lr = lane & 15, lg = lane >> 4;

    // ---- phase 0: stage X (f32->bf16 swizzled) + Mt weights ----
    {
        int t0 = tid & 63, cq = tid >> 6;
        const float* src = f + (size_t)(b * 128 + cq * 32) * HW + p0 + t0;
        float xv[32];
        #pragma unroll
        for (int i = 0; i < 32; ++i) xv[i] = src[(size_t)i * HW];
        int4 wreg[8];
        const int4* wsrc = (const int4*)MtB;
        #pragma unroll
        for (int j = 0; j < 8; ++j) wreg[j] = wsrc[j * 256 + tid];
        #pragma unroll
        for (int j = 0; j < 4; ++j) {
            int c0 = cq * 32 + j * 8;
            int4 v;
            v.x = pack2(xv[j * 8 + 0], xv[j * 8 + 1]);
            v.y = pack2(xv[j * 8 + 2], xv[j * 8 + 3]);
            v.z = pack2(xv[j * 8 + 4], xv[j * 8 + 5]);
            v.w = pack2(xv[j * 8 + 6], xv[j * 8 + 7]);
            *(int4*)(Xb + t0 * 256 + ((2 * c0) ^ ((t0 & 7) << 4))) = v;
        }
        #pragma unroll
        for (int j = 0; j < 8; ++j) {
            int ci = j * 256 + tid, n = ci >> 4, pos = ci & 15;
            *(int4*)(Wt + n * 256 + ((pos * 16) ^ ((n & 7) << 4))) = wreg[j];
        }
    }
    __syncthreads();  // B1

    int t = 16 * wid + lr;

    // ---- phase 1: XM^T = Mt(A,LDS) x X(B) -> XMb (wave-private rows) ----
    {
        f32x4 acc[8] = {};
        #pragma unroll
        for (int ks = 0; ks < 4; ++ks) {
            int k = ks * 32 + lg * 8;
            bfrag xb = ld256(Xb, t, k);
            #pragma unroll
            for (int ct = 0; ct < 8; ++ct) {
                bfrag am = ld256(Wt, 16 * ct + lr, k);
                acc[ct] = MFMA16(am, xb, acc[ct], 0, 0, 0);
            }
        }
        #pragma unroll
        for (int ct = 0; ct < 8; ++ct) {
            int c0 = 16 * ct + 4 * lg;
            int2 v; v.x = pack2(acc[ct][0], acc[ct][1]); v.y = pack2(acc[ct][2], acc[ct][3]);
            *(int2*)(XMb + t * 256 + ((2 * c0) ^ ((t & 7) << 4))) = v;
        }
    }
    __syncthreads();  // B2 (Mt reads done everywhere; XM rows are wave-private)

    // ---- phase 2: S^T + softmax; P overwrites own XM row (no barrier); Wvlt ----
    {
        int4 wreg[8];
        const int4* wsrc = (const int4*)WvltB;
        #pragma unroll
        for (int j = 0; j < 8; ++j) wreg[j] = wsrc[j * 256 + tid];

        f32x4 s[4] = {};
        #pragma unroll
        for (int ks = 0; ks < 4; ++ks) {
            int k = ks * 32 + lg * 8;
            bfrag bxm = ld256(XMb, t, k);
            #pragma unroll
            for (int ut = 0; ut < 4; ++ut) {
                bfrag ax = ld256(Xb, 16 * ut + lr, k);
                s[ut] = MFMA16(ax, bxm, s[ut], 0, 0, 0);
            }
        }
        float m = -1e30f;
        #pragma unroll
        for (int ut = 0; ut < 4; ++ut)
            #pragma unroll
            for (int r = 0; r < 4; ++r) m = fmaxf(m, s[ut][r]);
        m = fmaxf(m, __shfl_xor(m, 16));
        m = fmaxf(m, __shfl_xor(m, 32));
        float sum = 0.f;
        float e[4][4];
        #pragma unroll
        for (int ut = 0; ut < 4; ++ut)
            #pragma unroll
            for (int r = 0; r < 4; ++r) {
                e[ut][r] = __expf((s[ut][r] - m) * SCALE);
                sum += e[ut][r];
            }
        sum += __shfl_xor(sum, 16);
        sum += __shfl_xor(sum, 32);
        float pinv = 1.0f / sum;
        // P write into OWN XM row t (wave-private) — no block barrier needed.
        #pragma unroll
        for (int ut = 0; ut < 4; ++ut) {
            int u0 = 16 * ut + 4 * lg;
            int2 v;
            v.x = pack2(e[ut][0] * pinv, e[ut][1] * pinv);
            v.y = pack2(e[ut][2] * pinv, e[ut][3] * pinv);
            *(int2*)(XMb + t * 256 + ((2 * u0) ^ ((t & 7) << 4))) = v;
        }
        #pragma unroll
        for (int j = 0; j < 8; ++j) {
            int ci = j * 256 + tid, n = ci >> 4, pos = ci & 15;
            *(int4*)(Wt + n * 256 + ((pos * 16) ^ ((n & 7) << 4))) = wreg[j];
        }
    }
    __syncthreads();  // B3 (Wvlt visible)

    // ---- phase 3: V^T = X(A) x Wvlt(B,LDS) -> Vt; issue G1t loads ----
    int4 wregG[8];
    {
        const int4* wsrc = (const int4*)G1tB;
        #pragma unroll
        for (int j = 0; j < 8; ++j) wregG[j] = wsrc[j * 256 + tid];

        f32x4 vacc[8] = {};
        #pragma unroll
        for (int ks = 0; ks < 4; ++ks) {
            int k = ks * 32 + lg * 8;
            bfrag ax = ld256(Xb, t, k);
            #pragma unroll
            for (int ct = 0; ct < 8; ++ct) {
                bfrag bw = ld256(Wt, 16 * ct + lr, k);
                vacc[ct] = MFMA16(ax, bw, vacc[ct], 0, 0, 0);
            }
        }
        #pragma unroll
        for (int ct = 0; ct < 8; ++ct) {
            int c = 16 * ct + lr;
            int u0 = 16 * wid + 4 * lg;
            int2 v; v.x = pack2(vacc[ct][0], vacc[ct][1]); v.y = pack2(vacc[ct][2], vacc[ct][3]);
            *(int2*)(Vt + c * 128 + ((2 * u0) ^ ((c & 7) << 4))) = v;
        }
    }
    __syncthreads();  // B4 (Wvlt reads done; Vt visible)

    // ---- phase 4: stage G1t; Y^T = Vt(A) x P(B); yl = Y*X in-place; yg/g0 ----
    float yl[8][4];
    float4 yg4[8], g04[8];
    {
        #pragma unroll
        for (int j = 0; j < 8; ++j) {
            int ci = j * 256 + tid, n = ci >> 4, pos = ci & 15;
            *(int4*)(Wt + n * 256 + ((pos * 16) ^ ((n & 7) << 4))) = wregG[j];
        }
        size_t rbase = ((size_t)b * NWIN + w) * 128 + 4 * lg;
        #pragma unroll
        for (int nt = 0; nt < 8; ++nt) {
            yg4[nt] = *(const float4*)(ycen + rbase + 16 * nt);
            g04[nt] = *(const float4*)(g0g + rbase + 16 * nt);
        }
        f32x4 y[8] = {};
        #pragma unroll
        for (int us = 0; us < 2; ++us) {
            int u = us * 32 + lg * 8;
            bfrag bp = ld256(XMb, t, u);  // P (stride-256, own row)
            #pragma unroll
            for (int ct = 0; ct < 8; ++ct) {
                bfrag av = ld128(Vt, 16 * ct + lr, u);
                y[ct] = MFMA16(av, bp, y[ct], 0, 0, 0);
            }
        }
        #pragma unroll
        for (int ct = 0; ct < 8; ++ct) {
            int c0 = 16 * ct + 4 * lg;
            int2 xw = *(const int2*)(Xb + t * 256 + ((2 * c0) ^ ((t & 7) << 4)));
            float x0 = b2f((unsigned short)(xw.x & 0xffff));
            float x1 = b2f((unsigned short)((unsigned)xw.x >> 16));
            float x2 = b2f((unsigned short)(xw.y & 0xffff));
            float x3 = b2f((unsigned short)((unsigned)xw.y >> 16));
            yl[ct][0] = y[ct][0] * x0;
            yl[ct][1] = y[ct][1] * x1;
            yl[ct][2] = y[ct][2] * x2;
            yl[ct][3] = y[ct][3] * x3;
            int2 v; v.x = pack2(yl[ct][0], yl[ct][1]); v.y = pack2(yl[ct][2], yl[ct][3]);
            *(int2*)(Xb + t * 256 + ((2 * c0) ^ ((t & 7) << 4))) = v;  // in-place yl
        }
    }
    __syncthreads();  // B5 (G1t + yl visible)

    // ---- phase 5: G^T = G1t(A,LDS) x yl(B); alpha; blend + store ----
    {
        f32x4 g[8] = {};
        #pragma unroll
        for (int ks = 0; ks < 4; ++ks) {
            int k = ks * 32 + lg * 8;
            bfrag byl = ld256(Xb, t, k);  // yl
            #pragma unroll
            for (int nt = 0; nt < 8; ++nt) {
                bfrag ag = ld256(Wt, 16 * nt + lr, k);
                g[nt] = MFMA16(ag, byl, g[nt], 0, 0, 0);
            }
        }
        #pragma unroll
        for (int nt = 0; nt < 8; ++nt) {
            float gv[4] = {g04[nt].x, g04[nt].y, g04[nt].z, g04[nt].w};
            float yv4[4] = {yg4[nt].x, yg4[nt].y, yg4[nt].z, yg4[nt].w};
            #pragma unroll
            for (int r = 0; r < 4; ++r) {
                int c = 16 * nt + 4 * lg + r;
                float a = 1.0f / (1.0f + __expf(-(g[nt][r] + gv[r])));
                float yv = a * yv4[r] + (1.0f - a) * yl[nt][r];
                out[obase + (size_t)(b * 128 + c) * HW + p0 + t] = yv;
            }
        }
    }
}

// ---------- K6/K7 v4: conv3x3 + PixelShuffle + residual, MFMA fp16 ----------
// Weights never touch LDS: register double-buffered direct-L2 A-fragments.
template <int H, int W>
__global__ __launch_bounds__(256, 2) void k_conv_mfma(
    const float* __restrict__ in, const _Float16* __restrict__ Wcv,
    float* __restrict__ out) {
    constexpr int TXN = W / 32;
    int tile = blockIdx.x;
    int ty = tile / TXN, tx = tile % TXN;
    int y0 = ty * 4, x0 = tx * 32;
    int ob = blockIdx.y * 256;
    int b = blockIdx.z;

    __shared__ __align__(16) char sXs[16384];  // 204 rows x 80B, slot swz (row>>3)&1

    int tid = threadIdx.x;
    int wid = tid >> 6, lane = tid & 63;
    int lr = lane & 15, lg = lane >> 4;

    f32x4 acc[8][4] = {};

    int sy = tid / 34, sx = tid - sy * 34;
    int gy = y0 + sy - 1, gx = x0 + sx - 1;
    bool act = tid < 204;
    bool ok = act && gy >= 0 && gy < H && gx >= 0 && gx < W;
    const float* gp = in + (size_t)b * 128 * H * W + (size_t)gy * W + gx;
    int xswz = (tid >> 3) & 1;

    const _Float16* wbase = Wcv + (size_t)(ob + lr) * 32 + lg * 8;

    hfrag afC[4], afN[4];
    #pragma unroll
    for (int n = 0; n < 4; ++n)
        afC[n] = *(const hfrag*)(wbase + (size_t)(wid * 4 + n) * 512);

    if (act) {
        float xv[32];
        if (ok) {
            #pragma unroll
            for (int ic = 0; ic < 32; ++ic) xv[ic] = gp[(size_t)ic * H * W];
        } else {
            #pragma unroll
            for (int ic = 0; ic < 32; ++ic) xv[ic] = 0.f;
        }
        #pragma unroll
        for (int s = 0; s < 4; ++s) {
            _Float16 hh[8];
            #pragma unroll
            for (int e = 0; e < 8; ++e) hh[e] = (_Float16)xv[s * 8 + e];
            *(int4*)(sXs + tid * 80 + ((s ^ xswz) << 4)) = *(int4*)hh;
        }
    }
    __syncthreads();

    for (int ics = 0; ics < 4; ++ics) {
        if (ics) {
            __syncthreads();
            if (act) {
                float xv[32];
                if (ok) {
                    #pragma unroll
                    for (int ic = 0; ic < 32; ++ic)
                        xv[ic] = gp[(size_t)(ics * 32 + ic) * H * W];
                } else {
                    #pragma unroll
                    for (int ic = 0; ic < 32; ++ic) xv[ic] = 0.f;
                }
                #pragma unroll
                for (int s = 0; s < 4; ++s) {
                    _Float16 hh[8];
                    #pragma unroll
                    for (int e = 0; e < 8; ++e) hh[e] = (_Float16)xv[s * 8 + e];
                    *(int4*)(sXs + tid * 80 + ((s ^ xswz) << 4)) = *(int4*)hh;
                }
            }
            __syncthreads();
        }
        #pragma unroll
        for (int tap = 0; tap < 9; ++tap) {
            int kg = ics * 9 + tap;
            if (tap < 8 || ics < 3) {
                const _Float16* ws = wbase + (size_t)(kg + 1) * 16384;
                #pragma unroll
                for (int n = 0; n < 4; ++n)
                    afN[n] = *(const hfrag*)(ws + (size_t)(wid * 4 + n) * 512);
            }
            int dy = tap / 3, dx = tap - dy * 3;
            hfrag bf[8];
            #pragma unroll
            for (int m = 0; m < 8; ++m) {
                int row = ((m >> 1) + dy) * 34 + (m & 1) * 16 + lr + dx;
                bf[m] = *(const hfrag*)(sXs + row * 80 + ((lg ^ ((row >> 3) & 1)) << 4));
            }
            #pragma unroll
            for (int m = 0; m < 8; ++m)
                #pragma unroll
                for (int n = 0; n < 4; ++n)
                    acc[m][n] = MFMA16H(afC[n], bf[m], acc[m][n], 0, 0, 0);
            #pragma unroll
            for (int n = 0; n < 4; ++n) afC[n] = afN[n];
        }
    }

    float* outb = out + (size_t)b * 128 * 4 * H * W;
    #pragma unroll
    for (int n = 0; n < 4; ++n) {
        int oc0 = ob + (wid * 4 + n) * 16 + lg * 4;
        int c = oc0 >> 2;
        #pragma unroll
        for (int mr = 0; mr < 4; ++mr) {
            int py = y0 + mr;
            #pragma unroll
            for (int i2 = 0; i2 < 2; ++i2) {
                size_t rowb = ((size_t)c * (2 * H) + 2 * py + i2) * (2 * W);
                float2* p0 = (float2*)(outb + rowb + 2 * (x0 + lr));
                float2 v0 = *p0;
                v0.x += acc[2 * mr][n][i2 * 2 + 0];
                v0.y += acc[2 * mr][n][i2 * 2 + 1];
                *p0 = v0;
                float2* p1 = (float2*)(outb + rowb + 2 * (x0 + 16 + lr));
                float2 v1 = *p1;
                v1.x += acc[2 * mr + 1][n][i2 * 2 + 0];
                v1.y += acc[2 * mr + 1][n][i2 * 2 + 1];
                *p1 = v1;
            }
        }
    }
}

extern "C" void kernel_launch(void* const* d_in, const int* in_sizes, int n_in,
                              void* d_out, int out_size, void* d_ws, size_t ws_size,
                              hipStream_t stream) {
    const float* f0 = (const float*)d_in[0];
    const float* f1 = (const float*)d_in[1];
    const float* f2 = (const float*)d_in[2];
    const float* Wq = (const float*)d_in[3];
    const float* Wk = (const float*)d_in[4];
    const float* Wv = (const float*)d_in[5];
    const float* Wql = (const float*)d_in[6];
    const float* Wkl = (const float*)d_in[7];
    const float* Wvl = (const float*)d_in[8];
    const float* gate_w = (const float*)d_in[9];
    const float* conv0 = (const float*)d_in[10];
    const float* conv1 = (const float*)d_in[11];
    float* out = (float*)d_out;
    float* ws = (float*)d_ws;

    float* ctr = ws;                      // 688128 f32
    float* ycen = ctr + 688128;           // 688128 f32
    float* g0g = ycen + 688128;           // 688128 f32
    unsigned short* MtB = (unsigned short*)(g0g + 688128);   // 16384 bf16
    unsigned short* WvltB = MtB + 16384;                     // 16384 bf16
    unsigned short* G1tB = WvltB + 16384;                    // 16384 bf16
    unsigned short* G0tB = G1tB + 16384;                     // 16384 bf16
    unsigned short* MgtB = G0tB + 16384;                     // 16384 bf16
    unsigned short* WvtB = MgtB + 16384;                     // 16384 bf16
    _Float16* Wcv0 = (_Float16*)(WvtB + 16384);              // 589824 f16
    _Float16* Wcv1 = Wcv0 + 589824;                          // 589824 f16
    unsigned short* ctrb = (unsigned short*)(Wcv1 + 589824); // 688128 bf16
    unsigned short* Tgb = ctrb + 688128;                     // 688128 bf16
    unsigned short* Vgt = Tgb + 688128;                      // 4*128*NP bf16
    unsigned short* Pg = Vgt + 4 * 128 * NP;                 // 4*NWIN*NP bf16

    hipFuncSetAttribute((const void*)k_local_mfma,
                        hipFuncAttributeMaxDynamicSharedMemorySize, SMEM_SZ);
    hipFuncSetAttribute((const void*)k_qk,
                        hipFuncAttributeMaxDynamicSharedMemorySize, 32 * 1344 * 2);

    k_prep<<<dim3(128, 6), 128, 0, stream>>>(Wql, Wkl, Wvl, gate_w, Wq, Wk, Wv,
                                             MtB, WvltB, G1tB, G0tB, MgtB, WvtB);
    k_prep_conv<<<dim3(2304, 2), 256, 0, stream>>>(conv0, conv1, Wcv0, Wcv1);
    k_centers<<<dim3(NWIN, 4), 256, 0, stream>>>(f0, f1, f2, ctr, ctrb);
    k_tgvg2<<<dim3(NWIN / 32, 4), 256, 0, stream>>>(ctrb, MgtB, WvtB, Tgb, Vgt);
    k_qk<<<dim3(NWIN / 32, 4), 256, 32 * 1344 * 2, stream>>>(Tgb, ctrb, Pg);
    k_pvg0<<<dim3(NWIN / 32, 4), 256, 0, stream>>>(Pg, Vgt, ctr, G0tB, ycen, g0g);
    k_local_mfma<<<dim3(NWIN, 4), 256, SMEM_SZ, stream>>>(
        f0, f1, f2, MtB, WvltB, G1tB, g0g, ycen, out);
    k_conv_mfma<64, 64><<<dim3(32, 2, 4), 256, 0, stream>>>(out + OUT0, Wcv0, out + OUT1);
    k_conv_mfma<128, 128><<<dim3(128, 2, 4), 256, 0, stream>>>(out + OUT1, Wcv1, out + OUT2);
}

// Round 15
// 549.380 us; speedup vs baseline: 1.1553x; 1.0352x over previous
//
#include <hip/hip_runtime.h>
#include <math.h>

#define WT 64
#define NWIN 1344
#define NP 1408  // Vgt row stride
#define SROW_STRIDE 1352  // P/S LDS row stride (2-way-free banks)
constexpr float SCALE = 0.088388347648318447f;  // 128^-0.5

// out region offsets (floats)
#define OUT0 0
#define OUT1 2097152
#define OUT2 10485760

typedef __attribute__((ext_vector_type(8))) short bfrag;      // 8 bf16
typedef __attribute__((ext_vector_type(8))) _Float16 hfrag;   // 8 fp16
typedef __attribute__((ext_vector_type(4))) float f32x4;      // MFMA C/D

#define MFMA16 __builtin_amdgcn_mfma_f32_16x16x32_bf16
#define MFMA16H __builtin_amdgcn_mfma_f32_16x16x32_f16

__device__ __forceinline__ unsigned short f2b(float f) {
    union { float f; unsigned u; } v; v.f = f;
    unsigned r = v.u + 0x7fffu + ((v.u >> 16) & 1u);  // rne
    return (unsigned short)(r >> 16);
}
__device__ __forceinline__ float b2f(unsigned short u) {
    union { unsigned u; float f; } v; v.u = ((unsigned)u) << 16; return v.f;
}
__device__ __forceinline__ int pack2(float a, float b) {
    return (int)f2b(a) | ((int)f2b(b) << 16);
}

// swizzled LDS fragment loads: row-major bf16 tiles, byte ^= (row&7)<<4
__device__ __forceinline__ bfrag ld256(const char* region, int row, int k) {
    int off = (2 * k) ^ ((row & 7) << 4);
    return *(const bfrag*)(region + row * 256 + off);
}
__device__ __forceinline__ bfrag ld128(const char* region, int row, int k) {
    int off = (2 * k) ^ ((row & 7) << 4);
    return *(const bfrag*)(region + row * 128 + off);
}

// K1b: bf16 transposed weight prep (+ gate G0, + global-path Mgt/Wvt).
__global__ void k_prep(const float* __restrict__ Wql, const float* __restrict__ Wkl,
                       const float* __restrict__ Wvl, const float* __restrict__ gw,
                       const float* __restrict__ Wq, const float* __restrict__ Wk,
                       const float* __restrict__ Wv,
                       unsigned short* __restrict__ MtB,
                       unsigned short* __restrict__ WvltB,
                       unsigned short* __restrict__ G1tB,
                       unsigned short* __restrict__ G0tB,
                       unsigned short* __restrict__ MgtB,
                       unsigned short* __restrict__ WvtB) {
    int n = blockIdx.x, k = threadIdx.x;
    if (blockIdx.y == 0) {
        float a = 0.f;
        for (int c = 0; c < 128; ++c) a += Wkl[n * 128 + c] * Wql[k * 128 + c];
        MtB[n * 128 + k] = f2b(a);
    } else if (blockIdx.y == 1) {
        WvltB[n * 128 + k] = f2b(Wvl[k * 128 + n]);
    } else if (blockIdx.y == 2) {
        G1tB[n * 128 + k] = f2b(gw[(128 + k) * 128 + n]);
    } else if (blockIdx.y == 3) {
        G0tB[n * 128 + k] = f2b(gw[k * 128 + n]);
    } else if (blockIdx.y == 4) {
        float a = 0.f;
        for (int c = 0; c < 128; ++c) a += Wk[n * 128 + c] * Wq[k * 128 + c];
        MgtB[n * 128 + k] = f2b(a);
    } else {
        WvtB[n * 128 + k] = f2b(Wv[k * 128 + n]);
    }
}

// K1c: conv weight prep -> fp16 image [36 slices][512 oc][32 k]
__global__ __launch_bounds__(256) void k_prep_conv(
    const float* __restrict__ w0, const float* __restrict__ w1,
    _Float16* __restrict__ W0, _Float16* __restrict__ W1) {
    int idx = blockIdx.x * 256 + threadIdx.x;  // < 589824 = 36*512*32
    const float* w = blockIdx.y ? w1 : w0;
    _Float16* o = blockIdx.y ? W1 : W0;
    int slice = idx >> 14, rem = idx & 16383;
    int oc = rem >> 5, k = rem & 31;
    int ics = slice / 9, tap = slice - ics * 9;
    o[idx] = (_Float16)w[((size_t)oc * 128 + ics * 32 + k) * 9 + tap];
}

__device__ __forceinline__ void window_src(int n0, const float* f0, const float* f1,
                                           const float* f2, const float*& f, int& p0,
                                           int& HW, int& obase) {
    if (n0 < 4096)        { f = f0; p0 = n0;          HW = 4096;  obase = OUT0; }
    else if (n0 < 20480)  { f = f1; p0 = n0 - 4096;   HW = 16384; obase = OUT1; }
    else                  { f = f2; p0 = n0 - 20480;  HW = 65536; obase = OUT2; }
}

// K2: window means -> centers f32 [B,NWIN,128] + bf16 copy
__global__ __launch_bounds__(256) void k_centers(
    const float* __restrict__ f0, const float* __restrict__ f1,
    const float* __restrict__ f2, float* __restrict__ ctr,
    unsigned short* __restrict__ ctrb) {
    int w = blockIdx.x, b = blockIdx.y;
    const float* f; int p0, HW, ob;
    window_src(w * WT, f0, f1, f2, f, p0, HW, ob);
    int lane = threadIdx.x & 63, cg = threadIdx.x >> 6;
    for (int c = cg; c < 128; c += 4) {
        float v = f[(b * 128 + c) * HW + p0 + lane];
        #pragma unroll
        for (int off = 32; off; off >>= 1) v += __shfl_xor(v, off);
        if (lane == 0) {
            float mv = v * (1.0f / 64.0f);
            ctr[(b * NWIN + w) * 128 + c] = mv;
            ctrb[(b * NWIN + w) * 128 + c] = f2b(mv);
        }
    }
}

// K3 v3: Vgt = bf16((centers @ Wv)^T) [c][NP] only (Tg folded into k_qkpv)
__global__ __launch_bounds__(256) void k_vg(
    const unsigned short* __restrict__ ctrb, const unsigned short* __restrict__ WvtB,
    unsigned short* __restrict__ Vgt) {
    int blk = blockIdx.x, b = blockIdx.y;
    int mb = blk * 32;
    int tid = threadIdx.x, wid = tid >> 6, lane = tid & 63;
    int lr = lane & 15, lg = lane >> 4;
    int nb = wid * 32;
    f32x4 vg[2][2] = {};  // [ni][mj]
    const unsigned short* Cb = ctrb + ((size_t)b * NWIN + mb) * 128;
    #pragma unroll
    for (int ks = 0; ks < 4; ++ks) {
        int k = ks * 32 + lg * 8;
        bfrag b0 = *(const bfrag*)(Cb + lr * 128 + k);
        bfrag b1 = *(const bfrag*)(Cb + (16 + lr) * 128 + k);
        bfrag v0 = *(const bfrag*)(WvtB + (nb + lr) * 128 + k);
        bfrag v1 = *(const bfrag*)(WvtB + (nb + 16 + lr) * 128 + k);
        vg[0][0] = MFMA16(v0, b0, vg[0][0], 0, 0, 0);
        vg[0][1] = MFMA16(v0, b1, vg[0][1], 0, 0, 0);
        vg[1][0] = MFMA16(v1, b0, vg[1][0], 0, 0, 0);
        vg[1][1] = MFMA16(v1, b1, vg[1][1], 0, 0, 0);
    }
    #pragma unroll
    for (int ni = 0; ni < 2; ++ni)
        #pragma unroll
        for (int mj = 0; mj < 2; ++mj) {
            int n0 = nb + ni * 16 + 4 * lg;
            int m = mb + mj * 16 + lr;
            #pragma unroll
            for (int r = 0; r < 4; ++r)
                Vgt[((size_t)b * 128 + n0 + r) * NP + m] = f2b(vg[ni][mj][r]);
        }
}

// K4: fused global attention: Tg tile -> scores -> softmax (in LDS) -> PV ->
//     ycen (+bf16 Ys tile) -> g0.  No P/Tg global round-trips.
#define QKPV_LDS (32 * SROW_STRIDE * 2 + 8192)  // 94720 B

__global__ __launch_bounds__(256, 1) void k_qkpv(
    const unsigned short* __restrict__ ctrb, const unsigned short* __restrict__ MgtB,
    const unsigned short* __restrict__ Vgt, const unsigned short* __restrict__ G0tB,
    const float* __restrict__ ctr, float* __restrict__ ycen,
    float* __restrict__ g0g) {
    extern __shared__ char smem2[];
    unsigned short* Srow = (unsigned short*)smem2;      // [32][1352] S then P
    char* Ys = smem2 + 32 * SROW_STRIDE * 2;            // [32][256B] Tg then Y
    __shared__ float mxs[32], invs[32];
    int blk = blockIdx.x, b = blockIdx.y;
    int mb = blk * 32;
    int tid = threadIdx.x, wid = tid >> 6, lane = tid & 63;
    int lr = lane & 15, lg = lane >> 4;

    // Phase A: Tg tile = ctr[mb..mb+32) @ Mglob -> Ys (swizzled)
    {
        int nb = wid * 32;
        f32x4 tg[2][2] = {};
        const unsigned short* Cb = ctrb + ((size_t)b * NWIN + mb) * 128;
        #pragma unroll
        for (int ks = 0; ks < 4; ++ks) {
            int k = ks * 32 + lg * 8;
            bfrag b0 = *(const bfrag*)(Cb + lr * 128 + k);
            bfrag b1 = *(const bfrag*)(Cb + (16 + lr) * 128 + k);
            bfrag m0 = *(const bfrag*)(MgtB + (nb + lr) * 128 + k);
            bfrag m1 = *(const bfrag*)(MgtB + (nb + 16 + lr) * 128 + k);
            tg[0][0] = MFMA16(m0, b0, tg[0][0], 0, 0, 0);
            tg[0][1] = MFMA16(m0, b1, tg[0][1], 0, 0, 0);
            tg[1][0] = MFMA16(m1, b0, tg[1][0], 0, 0, 0);
            tg[1][1] = MFMA16(m1, b1, tg[1][1], 0, 0, 0);
        }
        #pragma unroll
        for (int ni = 0; ni < 2; ++ni)
            #pragma unroll
            for (int mj = 0; mj < 2; ++mj) {
                int n0 = nb + ni * 16 + 4 * lg;
                int m = mj * 16 + lr;
                int2 v; v.x = pack2(tg[ni][mj][0], tg[ni][mj][1]);
                v.y = pack2(tg[ni][mj][2], tg[ni][mj][3]);
                *(int2*)(Ys + m * 256 + ((2 * n0) ^ ((m & 7) << 4))) = v;
            }
    }
    __syncthreads();

    // Phase B: scores over all 1344 keys; A-frags from LDS Tg tile
    {
        int wm = (wid & 1) * 16, wn = (wid >> 1) * 32;
        for (int tile = 0; tile < 21; ++tile) {
            int nb = tile * 64 + wn;
            f32x4 acc[2] = {};
            #pragma unroll
            for (int ks = 0; ks < 4; ++ks) {
                int k = ks * 32 + lg * 8;
                bfrag a = ld256(Ys, wm + lr, k);
                #pragma unroll
                for (int nt = 0; nt < 2; ++nt) {
                    bfrag bb = *(const bfrag*)(ctrb + ((size_t)b * NWIN + nb + nt * 16 + lr) * 128 + k);
                    acc[nt] = MFMA16(a, bb, acc[nt], 0, 0, 0);
                }
            }
            #pragma unroll
            for (int nt = 0; nt < 2; ++nt) {
                int col = nb + nt * 16 + lr;
                #pragma unroll
                for (int r = 0; r < 4; ++r)
                    Srow[(wm + 4 * lg + r) * SROW_STRIDE + col] = f2b(acc[nt][r]);
            }
        }
    }
    __syncthreads();

    // Phase C: row max / sum, then in-place normalize (pad cols zeroed)
    {
        int row = tid >> 3, sub = tid & 7;
        const unsigned short* sr = Srow + row * SROW_STRIDE;
        float mx = -1e30f;
        for (int c = sub; c < 1344; c += 8) mx = fmaxf(mx, b2f(sr[c]));
        mx = fmaxf(mx, __shfl_xor(mx, 1));
        mx = fmaxf(mx, __shfl_xor(mx, 2));
        mx = fmaxf(mx, __shfl_xor(mx, 4));
        float sum = 0.f;
        for (int c = sub; c < 1344; c += 8) sum += __expf((b2f(sr[c]) - mx) * SCALE);
        sum += __shfl_xor(sum, 1);
        sum += __shfl_xor(sum, 2);
        sum += __shfl_xor(sum, 4);
        if (sub == 0) { mxs[row] = mx; invs[row] = 1.0f / sum; }
    }
    __syncthreads();
    for (int idx = tid; idx < 32 * (SROW_STRIDE / 8); idx += 256) {
        int row = idx / (SROW_STRIDE / 8), c8 = idx % (SROW_STRIDE / 8);
        float mx = mxs[row], inv = invs[row];
        unsigned short* sp = Srow + row * SROW_STRIDE + c8 * 8;
        unsigned short o[8];
        #pragma unroll
        for (int e = 0; e < 8; ++e) {
            int c = c8 * 8 + e;
            float p = (c < 1344) ? __expf((b2f(sp[e]) - mx) * SCALE) * inv : 0.f;
            o[e] = f2b(p);
        }
        *(int4*)sp = *(int4*)o;
    }
    __syncthreads();

    // Phase D: Y^T = Vgt x P^T (P from LDS, 42 exact iters); ycen + Ys stage
    {
        int cb = wid * 32;
        f32x4 acc[2][2] = {};
        const unsigned short* Vb = Vgt + (size_t)b * 128 * NP;
        for (int it = 0; it < 42; ++it) {
            int k = it * 32 + lg * 8;
            bfrag a0 = *(const bfrag*)(Vb + (size_t)(cb + lr) * NP + k);
            bfrag a1 = *(const bfrag*)(Vb + (size_t)(cb + 16 + lr) * NP + k);
            bfrag b0 = *(const bfrag*)(Srow + lr * SROW_STRIDE + k);
            bfrag b1 = *(const bfrag*)(Srow + (16 + lr) * SROW_STRIDE + k);
            acc[0][0] = MFMA16(a0, b0, acc[0][0], 0, 0, 0);
            acc[0][1] = MFMA16(a0, b1, acc[0][1], 0, 0, 0);
            acc[1][0] = MFMA16(a1, b0, acc[1][0], 0, 0, 0);
            acc[1][1] = MFMA16(a1, b1, acc[1][1], 0, 0, 0);
        }
        #pragma unroll
        for (int ci = 0; ci < 2; ++ci)
            #pragma unroll
            for (int mj = 0; mj < 2; ++mj) {
                int c0 = cb + ci * 16 + 4 * lg;
                int mr = mj * 16 + lr;
                int m = mb + mr;
                size_t base = ((size_t)b * NWIN + m) * 128 + c0;
                float4 cv = *(const float4*)(ctr + base);
                float4 y;
                y.x = acc[ci][mj][0] * cv.x;
                y.y = acc[ci][mj][1] * cv.y;
                y.z = acc[ci][mj][2] * cv.z;
                y.w = acc[ci][mj][3] * cv.w;
                *(float4*)(ycen + base) = y;
                int2 pv; pv.x = pack2(y.x, y.y); pv.y = pack2(y.z, y.w);
                *(int2*)(Ys + mr * 256 + ((2 * c0) ^ ((mr & 7) << 4))) = pv;
            }
    }
    __syncthreads();

    // Phase E: g0 = Y @ G0
    {
        int nb = wid * 32;
        f32x4 g[2][2] = {};
        #pragma unroll
        for (int ks = 0; ks < 4; ++ks) {
            int k = ks * 32 + lg * 8;
            bfrag a0 = *(const bfrag*)(G0tB + (nb + lr) * 128 + k);
            bfrag a1 = *(const bfrag*)(G0tB + (nb + 16 + lr) * 128 + k);
            bfrag b0 = ld256(Ys, lr, k);
            bfrag b1 = ld256(Ys, 16 + lr, k);
            g[0][0] = MFMA16(a0, b0, g[0][0], 0, 0, 0);
            g[0][1] = MFMA16(a0, b1, g[0][1], 0, 0, 0);
            g[1][0] = MFMA16(a1, b0, g[1][0], 0, 0, 0);
            g[1][1] = MFMA16(a1, b1, g[1][1], 0, 0, 0);
        }
        #pragma unroll
        for (int ni = 0; ni < 2; ++ni)
            #pragma unroll
            for (int mj = 0; mj < 2; ++mj) {
                int m = mb + mj * 16 + lr;
                int n0 = nb + ni * 16 + 4 * lg;
                #pragma unroll
                for (int r = 0; r < 4; ++r)
                    g0g[((size_t)b * NWIN + m) * 128 + n0 + r] = g[ni][mj][r];
            }
    }
}

// ---------- K5: fused local window attention via MFMA (80 KB, 2 blocks/CU) ----
// 5 barriers; P stored inside XM row t (wave-private).
#define XB_OFF 0
#define WT_OFF 16384
#define XM_OFF 49152
#define VT_OFF 65536
#define SMEM_SZ 81920

__global__ __launch_bounds__(256, 2) void k_local_mfma(
    const float* __restrict__ f0, const float* __restrict__ f1,
    const float* __restrict__ f2,
    const unsigned short* __restrict__ MtB,
    const unsigned short* __restrict__ WvltB,
    const unsigned short* __restrict__ G1tB,
    const float* __restrict__ g0g, const float* __restrict__ ycen,
    float* __restrict__ out) {
    extern __shared__ char smem[];
    char* Xb = smem + XB_OFF;    // X; yl in-place during phase 4
    char* Wt = smem + WT_OFF;    // Mt -> Wvlt -> G1t
    char* XMb = smem + XM_OFF;   // XM; P lives in row t's first 128 B (wave-private)
    char* Vt = smem + VT_OFF;

    int w = blockIdx.x, b = blockIdx.y;
    const float* f; int p0, HW, obase;
    window_src(w * WT, f0, f1, f2, f, p0, HW, obase);

    int tid = threadIdx.x;
    int wid = tid >> 6, lane = tid & 63;
    int lr = lane & 15, lg = lane >> 4;

    // ---- phase 0: stage X (f32->bf16 swizzled) + Mt weights ----
    {
        int t0 = tid & 63, cq = tid >> 6;
        const float* src = f + (size_t)(b * 128 + cq * 32) * HW + p0 + t0;
        float xv[32];
        #pragma unroll
        for (int i = 0; i < 32; ++i) xv[i] = src[(size_t)i * HW];
        int4 wreg[8];
        const int4* wsrc = (const int4*)MtB;
        #pragma unroll
        for (int j = 0; j < 8; ++j) wreg[j] = wsrc[j * 256 + tid];
        #pragma unroll
        for (int j = 0; j < 4; ++j) {
            int c0 = cq * 32 + j * 8;
            int4 v;
            v.x = pack2(xv[j * 8 + 0], xv[j * 8 + 1]);
            v.y = pack2(xv[j * 8 + 2], xv[j * 8 + 3]);
            v.z = pack2(xv[j * 8 + 4], xv[j * 8 + 5]);
            v.w = pack2(xv[j * 8 + 6], xv[j * 8 + 7]);
            *(int4*)(Xb + t0 * 256 + ((2 * c0) ^ ((t0 & 7) << 4))) = v;
        }
        #pragma unroll
        for (int j = 0; j < 8; ++j) {
            int ci = j * 256 + tid, n = ci >> 4, pos = ci & 15;
            *(int4*)(Wt + n * 256 + ((pos * 16) ^ ((n & 7) << 4))) = wreg[j];
        }
    }
    __syncthreads();  // B1

    int t = 16 * wid + lr;

    // ---- phase 1: XM^T = Mt(A,LDS) x X(B) -> XMb (wave-private rows) ----
    {
        f32x4 acc[8] = {};
        #pragma unroll
        for (int ks = 0; ks < 4; ++ks) {
            int k = ks * 32 + lg * 8;
            bfrag xb = ld256(Xb, t, k);
            #pragma unroll
            for (int ct = 0; ct < 8; ++ct) {
                bfrag am = ld256(Wt, 16 * ct + lr, k);
                acc[ct] = MFMA16(am, xb, acc[ct], 0, 0, 0);
            }
        }
        #pragma unroll
        for (int ct = 0; ct < 8; ++ct) {
            int c0 = 16 * ct + 4 * lg;
            int2 v; v.x = pack2(acc[ct][0], acc[ct][1]); v.y = pack2(acc[ct][2], acc[ct][3]);
            *(int2*)(XMb + t * 256 + ((2 * c0) ^ ((t & 7) << 4))) = v;
        }
    }
    __syncthreads();  // B2

    // ---- phase 2: S^T + softmax; P overwrites own XM row (no barrier); Wvlt ----
    {
        int4 wreg[8];
        const int4* wsrc = (const int4*)WvltB;
        #pragma unroll
        for (int j = 0; j < 8; ++j) wreg[j] = wsrc[j * 256 + tid];

        f32x4 s[4] = {};
        #pragma unroll
        for (int ks = 0; ks < 4; ++ks) {
            int k = ks * 32 + lg * 8;
            bfrag bxm = ld256(XMb, t, k);
            #pragma unroll
            for (int ut = 0; ut < 4; ++ut) {
                bfrag ax = ld256(Xb, 16 * ut + lr, k);
                s[ut] = MFMA16(ax, bxm, s[ut], 0, 0, 0);
            }
        }
        float m = -1e30f;
        #pragma unroll
        for (int ut = 0; ut < 4; ++ut)
            #pragma unroll
            for (int r = 0; r < 4; ++r) m = fmaxf(m, s[ut][r]);
        m = fmaxf(m, __shfl_xor(m, 16));
        m = fmaxf(m, __shfl_xor(m, 32));
        float sum = 0.f;
        float e[4][4];
        #pragma unroll
        for (int ut = 0; ut < 4; ++ut)
            #pragma unroll
            for (int r = 0; r < 4; ++r) {
                e[ut][r] = __expf((s[ut][r] - m) * SCALE);
                sum += e[ut][r];
            }
        sum += __shfl_xor(sum, 16);
        sum += __shfl_xor(sum, 32);
        float pinv = 1.0f / sum;
        #pragma unroll
        for (int ut = 0; ut < 4; ++ut) {
            int u0 = 16 * ut + 4 * lg;
            int2 v;
            v.x = pack2(e[ut][0] * pinv, e[ut][1] * pinv);
            v.y = pack2(e[ut][2] * pinv, e[ut][3] * pinv);
            *(int2*)(XMb + t * 256 + ((2 * u0) ^ ((t & 7) << 4))) = v;
        }
        #pragma unroll
        for (int j = 0; j < 8; ++j) {
            int ci = j * 256 + tid, n = ci >> 4, pos = ci & 15;
            *(int4*)(Wt + n * 256 + ((pos * 16) ^ ((n & 7) << 4))) = wreg[j];
        }
    }
    __syncthreads();  // B3 (Wvlt visible)

    // ---- phase 3: V^T = X(A) x Wvlt(B,LDS) -> Vt; issue G1t loads ----
    int4 wregG[8];
    {
        const int4* wsrc = (const int4*)G1tB;
        #pragma unroll
        for (int j = 0; j < 8; ++j) wregG[j] = wsrc[j * 256 + tid];

        f32x4 vacc[8] = {};
        #pragma unroll
        for (int ks = 0; ks < 4; ++ks) {
            int k = ks * 32 + lg * 8;
            bfrag ax = ld256(Xb, t, k);
            #pragma unroll
            for (int ct = 0; ct < 8; ++ct) {
                bfrag bw = ld256(Wt, 16 * ct + lr, k);
                vacc[ct] = MFMA16(ax, bw, vacc[ct], 0, 0, 0);
            }
        }
        #pragma unroll
        for (int ct = 0; ct < 8; ++ct) {
            int c = 16 * ct + lr;
            int u0 = 16 * wid + 4 * lg;
            int2 v; v.x = pack2(vacc[ct][0], vacc[ct][1]); v.y = pack2(vacc[ct][2], vacc[ct][3]);
            *(int2*)(Vt + c * 128 + ((2 * u0) ^ ((c & 7) << 4))) = v;
        }
    }
    __syncthreads();  // B4

    // ---- phase 4: stage G1t; Y^T = Vt(A) x P(B); yl = Y*X in-place; yg/g0 ----
    float yl[8][4];
    float4 yg4[8], g04[8];
    {
        #pragma unroll
        for (int j = 0; j < 8; ++j) {
            int ci = j * 256 + tid, n = ci >> 4, pos = ci & 15;
            *(int4*)(Wt + n * 256 + ((pos * 16) ^ ((n & 7) << 4))) = wregG[j];
        }
        size_t rbase = ((size_t)b * NWIN + w) * 128 + 4 * lg;
        #pragma unroll
        for (int nt = 0; nt < 8; ++nt) {
            yg4[nt] = *(const float4*)(ycen + rbase + 16 * nt);
            g04[nt] = *(const float4*)(g0g + rbase + 16 * nt);
        }
        f32x4 y[8] = {};
        #pragma unroll
        for (int us = 0; us < 2; ++us) {
            int u = us * 32 + lg * 8;
            bfrag bp = ld256(XMb, t, u);  // P (stride-256, own row)
            #pragma unroll
            for (int ct = 0; ct < 8; ++ct) {
                bfrag av = ld128(Vt, 16 * ct + lr, u);
                y[ct] = MFMA16(av, bp, y[ct], 0, 0, 0);
            }
        }
        #pragma unroll
        for (int ct = 0; ct < 8; ++ct) {
            int c0 = 16 * ct + 4 * lg;
            int2 xw = *(const int2*)(Xb + t * 256 + ((2 * c0) ^ ((t & 7) << 4)));
            float x0 = b2f((unsigned short)(xw.x & 0xffff));
            float x1 = b2f((unsigned short)((unsigned)xw.x >> 16));
            float x2 = b2f((unsigned short)(xw.y & 0xffff));
            float x3 = b2f((unsigned short)((unsigned)xw.y >> 16));
            yl[ct][0] = y[ct][0] * x0;
            yl[ct][1] = y[ct][1] * x1;
            yl[ct][2] = y[ct][2] * x2;
            yl[ct][3] = y[ct][3] * x3;
            int2 v; v.x = pack2(yl[ct][0], yl[ct][1]); v.y = pack2(yl[ct][2], yl[ct][3]);
            *(int2*)(Xb + t * 256 + ((2 * c0) ^ ((t & 7) << 4))) = v;  // in-place yl
        }
    }
    __syncthreads();  // B5

    // ---- phase 5: G^T = G1t(A,LDS) x yl(B); alpha; blend + store ----
    {
        f32x4 g[8] = {};
        #pragma unroll
        for (int ks = 0; ks < 4; ++ks) {
            int k = ks * 32 + lg * 8;
            bfrag byl = ld256(Xb, t, k);  // yl
            #pragma unroll
            for (int nt = 0; nt < 8; ++nt) {
                bfrag ag = ld256(Wt, 16 * nt + lr, k);
                g[nt] = MFMA16(ag, byl, g[nt], 0, 0, 0);
            }
        }
        #pragma unroll
        for (int nt = 0; nt < 8; ++nt) {
            float gv[4] = {g04[nt].x, g04[nt].y, g04[nt].z, g04[nt].w};
            float yv4[4] = {yg4[nt].x, yg4[nt].y, yg4[nt].z, yg4[nt].w};
            #pragma unroll
            for (int r = 0; r < 4; ++r) {
                int c = 16 * nt + 4 * lg + r;
                float a = 1.0f / (1.0f + __expf(-(g[nt][r] + gv[r])));
                float yv = a * yv4[r] + (1.0f - a) * yl[nt][r];
                out[obase + (size_t)(b * 128 + c) * HW + p0 + t] = yv;
            }
        }
    }
}

// ---------- K6/K7 v4: conv3x3 + PixelShuffle + residual, MFMA fp16 ----------
template <int H, int W>
__global__ __launch_bounds__(256, 2) void k_conv_mfma(
    const float* __restrict__ in, const _Float16* __restrict__ Wcv,
    float* __restrict__ out) {
    constexpr int TXN = W / 32;
    int tile = blockIdx.x;
    int ty = tile / TXN, tx = tile % TXN;
    int y0 = ty * 4, x0 = tx * 32;
    int ob = blockIdx.y * 256;
    int b = blockIdx.z;

    __shared__ __align__(16) char sXs[16384];  // 204 rows x 80B, slot swz (row>>3)&1

    int tid = threadIdx.x;
    int wid = tid >> 6, lane = tid & 63;
    int lr = lane & 15, lg = lane >> 4;

    f32x4 acc[8][4] = {};

    int sy = tid / 34, sx = tid - sy * 34;
    int gy = y0 + sy - 1, gx = x0 + sx - 1;
    bool act = tid < 204;
    bool ok = act && gy >= 0 && gy < H && gx >= 0 && gx < W;
    const float* gp = in + (size_t)b * 128 * H * W + (size_t)gy * W + gx;
    int xswz = (tid >> 3) & 1;

    const _Float16* wbase = Wcv + (size_t)(ob + lr) * 32 + lg * 8;

    hfrag afC[4], afN[4];
    #pragma unroll
    for (int n = 0; n < 4; ++n)
        afC[n] = *(const hfrag*)(wbase + (size_t)(wid * 4 + n) * 512);

    if (act) {
        float xv[32];
        if (ok) {
            #pragma unroll
            for (int ic = 0; ic < 32; ++ic) xv[ic] = gp[(size_t)ic * H * W];
        } else {
            #pragma unroll
            for (int ic = 0; ic < 32; ++ic) xv[ic] = 0.f;
        }
        #pragma unroll
        for (int s = 0; s < 4; ++s) {
            _Float16 hh[8];
            #pragma unroll
            for (int e = 0; e < 8; ++e) hh[e] = (_Float16)xv[s * 8 + e];
            *(int4*)(sXs + tid * 80 + ((s ^ xswz) << 4)) = *(int4*)hh;
        }
    }
    __syncthreads();

    for (int ics = 0; ics < 4; ++ics) {
        if (ics) {
            __syncthreads();
            if (act) {
                float xv[32];
                if (ok) {
                    #pragma unroll
                    for (int ic = 0; ic < 32; ++ic)
                        xv[ic] = gp[(size_t)(ics * 32 + ic) * H * W];
                } else {
                    #pragma unroll
                    for (int ic = 0; ic < 32; ++ic) xv[ic] = 0.f;
                }
                #pragma unroll
                for (int s = 0; s < 4; ++s) {
                    _Float16 hh[8];
                    #pragma unroll
                    for (int e = 0; e < 8; ++e) hh[e] = (_Float16)xv[s * 8 + e];
                    *(int4*)(sXs + tid * 80 + ((s ^ xswz) << 4)) = *(int4*)hh;
                }
            }
            __syncthreads();
        }
        #pragma unroll
        for (int tap = 0; tap < 9; ++tap) {
            int kg = ics * 9 + tap;
            if (tap < 8 || ics < 3) {
                const _Float16* ws = wbase + (size_t)(kg + 1) * 16384;
                #pragma unroll
                for (int n = 0; n < 4; ++n)
                    afN[n] = *(const hfrag*)(ws + (size_t)(wid * 4 + n) * 512);
            }
            int dy = tap / 3, dx = tap - dy * 3;
            hfrag bf[8];
            #pragma unroll
            for (int m = 0; m < 8; ++m) {
                int row = ((m >> 1) + dy) * 34 + (m & 1) * 16 + lr + dx;
                bf[m] = *(const hfrag*)(sXs + row * 80 + ((lg ^ ((row >> 3) & 1)) << 4));
            }
            #pragma unroll
            for (int m = 0; m < 8; ++m)
                #pragma unroll
                for (int n = 0; n < 4; ++n)
                    acc[m][n] = MFMA16H(afC[n], bf[m], acc[m][n], 0, 0, 0);
            #pragma unroll
            for (int n = 0; n < 4; ++n) afC[n] = afN[n];
        }
    }

    float* outb = out + (size_t)b * 128 * 4 * H * W;
    #pragma unroll
    for (int n = 0; n < 4; ++n) {
        int oc0 = ob + (wid * 4 + n) * 16 + lg * 4;
        int c = oc0 >> 2;
        #pragma unroll
        for (int mr = 0; mr < 4; ++mr) {
            int py = y0 + mr;
            #pragma unroll
            for (int i2 = 0; i2 < 2; ++i2) {
                size_t rowb = ((size_t)c * (2 * H) + 2 * py + i2) * (2 * W);
                float2* p0 = (float2*)(outb + rowb + 2 * (x0 + lr));
                float2 v0 = *p0;
                v0.x += acc[2 * mr][n][i2 * 2 + 0];
                v0.y += acc[2 * mr][n][i2 * 2 + 1];
                *p0 = v0;
                float2* p1 = (float2*)(outb + rowb + 2 * (x0 + 16 + lr));
                float2 v1 = *p1;
                v1.x += acc[2 * mr + 1][n][i2 * 2 + 0];
                v1.y += acc[2 * mr + 1][n][i2 * 2 + 1];
                *p1 = v1;
            }
        }
    }
}

extern "C" void kernel_launch(void* const* d_in, const int* in_sizes, int n_in,
                              void* d_out, int out_size, void* d_ws, size_t ws_size,
                              hipStream_t stream) {
    const float* f0 = (const float*)d_in[0];
    const float* f1 = (const float*)d_in[1];
    const float* f2 = (const float*)d_in[2];
    const float* Wq = (const float*)d_in[3];
    const float* Wk = (const float*)d_in[4];
    const float* Wv = (const float*)d_in[5];
    const float* Wql = (const float*)d_in[6];
    const float* Wkl = (const float*)d_in[7];
    const float* Wvl = (const float*)d_in[8];
    const float* gate_w = (const float*)d_in[9];
    const float* conv0 = (const float*)d_in[10];
    const float* conv1 = (const float*)d_in[11];
    float* out = (float*)d_out;
    float* ws = (float*)d_ws;

    float* ctr = ws;                      // 688128 f32
    float* ycen = ctr + 688128;           // 688128 f32
    float* g0g = ycen + 688128;           // 688128 f32
    unsigned short* MtB = (unsigned short*)(g0g + 688128);   // 16384 bf16
    unsigned short* WvltB = MtB + 16384;                     // 16384 bf16
    unsigned short* G1tB = WvltB + 16384;                    // 16384 bf16
    unsigned short* G0tB = G1tB + 16384;                     // 16384 bf16
    unsigned short* MgtB = G0tB + 16384;                     // 16384 bf16
    unsigned short* WvtB = MgtB + 16384;                     // 16384 bf16
    _Float16* Wcv0 = (_Float16*)(WvtB + 16384);              // 589824 f16
    _Float16* Wcv1 = Wcv0 + 589824;                          // 589824 f16
    unsigned short* ctrb = (unsigned short*)(Wcv1 + 589824); // 688128 bf16
    unsigned short* Vgt = ctrb + 688128;                     // 4*128*NP bf16

    hipFuncSetAttribute((const void*)k_local_mfma,
                        hipFuncAttributeMaxDynamicSharedMemorySize, SMEM_SZ);
    hipFuncSetAttribute((const void*)k_qkpv,
                        hipFuncAttributeMaxDynamicSharedMemorySize, QKPV_LDS);

    k_prep<<<dim3(128, 6), 128, 0, stream>>>(Wql, Wkl, Wvl, gate_w, Wq, Wk, Wv,
                                             MtB, WvltB, G1tB, G0tB, MgtB, WvtB);
    k_prep_conv<<<dim3(2304, 2), 256, 0, stream>>>(conv0, conv1, Wcv0, Wcv1);
    k_centers<<<dim3(NWIN, 4), 256, 0, stream>>>(f0, f1, f2, ctr, ctrb);
    k_vg<<<dim3(NWIN / 32, 4), 256, 0, stream>>>(ctrb, WvtB, Vgt);
    k_qkpv<<<dim3(NWIN / 32, 4), 256, QKPV_LDS, stream>>>(
        ctrb, MgtB, Vgt, G0tB, ctr, ycen, g0g);
    k_local_mfma<<<dim3(NWIN, 4), 256, SMEM_SZ, stream>>>(
        f0, f1, f2, MtB, WvltB, G1tB, g0g, ycen, out);
    k_conv_mfma<64, 64><<<dim3(32, 2, 4), 256, 0, stream>>>(out + OUT0, Wcv0, out + OUT1);
    k_conv_mfma<128, 128><<<dim3(128, 2, 4), 256, 0, stream>>>(out + OUT1, Wcv1, out + OUT2);
}

// Round 16
// 529.632 us; speedup vs baseline: 1.1984x; 1.0373x over previous
//
#include <hip/hip_runtime.h>
#include <math.h>

#define WT 64
#define NWIN 1344
#define NP 1408  // Vgt row stride
#define SROW_STRIDE 1352  // P/S LDS row stride (2-way-free banks)
constexpr float SCALE = 0.088388347648318447f;  // 128^-0.5

// out region offsets (floats)
#define OUT0 0
#define OUT1 2097152
#define OUT2 10485760

typedef __attribute__((ext_vector_type(8))) short bfrag;      // 8 bf16
typedef __attribute__((ext_vector_type(8))) _Float16 hfrag;   // 8 fp16
typedef __attribute__((ext_vector_type(4))) float f32x4;      // MFMA C/D

#define MFMA16 __builtin_amdgcn_mfma_f32_16x16x32_bf16
#define MFMA16H __builtin_amdgcn_mfma_f32_16x16x32_f16

__device__ __forceinline__ unsigned short f2b(float f) {
    union { float f; unsigned u; } v; v.f = f;
    unsigned r = v.u + 0x7fffu + ((v.u >> 16) & 1u);  // rne
    return (unsigned short)(r >> 16);
}
__device__ __forceinline__ float b2f(unsigned short u) {
    union { unsigned u; float f; } v; v.u = ((unsigned)u) << 16; return v.f;
}
__device__ __forceinline__ int pack2(float a, float b) {
    return (int)f2b(a) | ((int)f2b(b) << 16);
}

// swizzled LDS fragment loads: row-major bf16 tiles, byte ^= (row&7)<<4
__device__ __forceinline__ bfrag ld256(const char* region, int row, int k) {
    int off = (2 * k) ^ ((row & 7) << 4);
    return *(const bfrag*)(region + row * 256 + off);
}
__device__ __forceinline__ bfrag ld128(const char* region, int row, int k) {
    int off = (2 * k) ^ ((row & 7) << 4);
    return *(const bfrag*)(region + row * 128 + off);
}

// K1: merged weight prep: conv images (y=0,1) + attention weight preps (y=2).
__global__ __launch_bounds__(256) void k_prep_all(
    const float* __restrict__ w0, const float* __restrict__ w1,
    _Float16* __restrict__ W0, _Float16* __restrict__ W1,
    const float* __restrict__ Wql, const float* __restrict__ Wkl,
    const float* __restrict__ Wvl, const float* __restrict__ gw,
    const float* __restrict__ Wq, const float* __restrict__ Wk,
    const float* __restrict__ Wv,
    unsigned short* __restrict__ MtB, unsigned short* __restrict__ WvltB,
    unsigned short* __restrict__ G1tB, unsigned short* __restrict__ G0tB,
    unsigned short* __restrict__ MgtB, unsigned short* __restrict__ WvtB) {
    if (blockIdx.y < 2) {
        int idx = blockIdx.x * 256 + threadIdx.x;  // < 589824 = 36*512*32
        const float* w = blockIdx.y ? w1 : w0;
        _Float16* o = blockIdx.y ? W1 : W0;
        int slice = idx >> 14, rem = idx & 16383;
        int oc = rem >> 5, k = rem & 31;
        int ics = slice / 9, tap = slice - ics * 9;
        o[idx] = (_Float16)w[((size_t)oc * 128 + ics * 32 + k) * 9 + tap];
        return;
    }
    if (blockIdx.x >= 384) return;
    int idx = blockIdx.x * 256 + threadIdx.x;  // < 98304 = 6*16384
    int k = idx & 127, n = (idx >> 7) & 127, v = idx >> 14;
    if (v == 0) {
        float a = 0.f;
        for (int c = 0; c < 128; ++c) a += Wkl[n * 128 + c] * Wql[k * 128 + c];
        MtB[n * 128 + k] = f2b(a);
    } else if (v == 1) {
        WvltB[n * 128 + k] = f2b(Wvl[k * 128 + n]);
    } else if (v == 2) {
        G1tB[n * 128 + k] = f2b(gw[(128 + k) * 128 + n]);
    } else if (v == 3) {
        G0tB[n * 128 + k] = f2b(gw[k * 128 + n]);
    } else if (v == 4) {
        float a = 0.f;
        for (int c = 0; c < 128; ++c) a += Wk[n * 128 + c] * Wq[k * 128 + c];
        MgtB[n * 128 + k] = f2b(a);
    } else {
        WvtB[n * 128 + k] = f2b(Wv[k * 128 + n]);
    }
}

__device__ __forceinline__ void window_src(int n0, const float* f0, const float* f1,
                                           const float* f2, const float*& f, int& p0,
                                           int& HW, int& obase) {
    if (n0 < 4096)        { f = f0; p0 = n0;          HW = 4096;  obase = OUT0; }
    else if (n0 < 20480)  { f = f1; p0 = n0 - 4096;   HW = 16384; obase = OUT1; }
    else                  { f = f2; p0 = n0 - 20480;  HW = 65536; obase = OUT2; }
}

// K2: window means -> centers f32 [B,NWIN,128] + bf16 copy
__global__ __launch_bounds__(256) void k_centers(
    const float* __restrict__ f0, const float* __restrict__ f1,
    const float* __restrict__ f2, float* __restrict__ ctr,
    unsigned short* __restrict__ ctrb) {
    int w = blockIdx.x, b = blockIdx.y;
    const float* f; int p0, HW, ob;
    window_src(w * WT, f0, f1, f2, f, p0, HW, ob);
    int lane = threadIdx.x & 63, cg = threadIdx.x >> 6;
    for (int c = cg; c < 128; c += 4) {
        float v = f[(b * 128 + c) * HW + p0 + lane];
        #pragma unroll
        for (int off = 32; off; off >>= 1) v += __shfl_xor(v, off);
        if (lane == 0) {
            float mv = v * (1.0f / 64.0f);
            ctr[(b * NWIN + w) * 128 + c] = mv;
            ctrb[(b * NWIN + w) * 128 + c] = f2b(mv);
        }
    }
}

// K3: Vgt = bf16((centers @ Wv)^T) [c][NP]
__global__ __launch_bounds__(256) void k_vg(
    const unsigned short* __restrict__ ctrb, const unsigned short* __restrict__ WvtB,
    unsigned short* __restrict__ Vgt) {
    int blk = blockIdx.x, b = blockIdx.y;
    int mb = blk * 32;
    int tid = threadIdx.x, wid = tid >> 6, lane = tid & 63;
    int lr = lane & 15, lg = lane >> 4;
    int nb = wid * 32;
    f32x4 vg[2][2] = {};  // [ni][mj]
    const unsigned short* Cb = ctrb + ((size_t)b * NWIN + mb) * 128;
    #pragma unroll
    for (int ks = 0; ks < 4; ++ks) {
        int k = ks * 32 + lg * 8;
        bfrag b0 = *(const bfrag*)(Cb + lr * 128 + k);
        bfrag b1 = *(const bfrag*)(Cb + (16 + lr) * 128 + k);
        bfrag v0 = *(const bfrag*)(WvtB + (nb + lr) * 128 + k);
        bfrag v1 = *(const bfrag*)(WvtB + (nb + 16 + lr) * 128 + k);
        vg[0][0] = MFMA16(v0, b0, vg[0][0], 0, 0, 0);
        vg[0][1] = MFMA16(v0, b1, vg[0][1], 0, 0, 0);
        vg[1][0] = MFMA16(v1, b0, vg[1][0], 0, 0, 0);
        vg[1][1] = MFMA16(v1, b1, vg[1][1], 0, 0, 0);
    }
    #pragma unroll
    for (int ni = 0; ni < 2; ++ni)
        #pragma unroll
        for (int mj = 0; mj < 2; ++mj) {
            int n0 = nb + ni * 16 + 4 * lg;
            int m = mb + mj * 16 + lr;
            #pragma unroll
            for (int r = 0; r < 4; ++r)
                Vgt[((size_t)b * 128 + n0 + r) * NP + m] = f2b(vg[ni][mj][r]);
        }
}

// K4: fused global attention: Tg tile -> scores -> softmax (in LDS) -> PV ->
//     ycen (+bf16 Ys tile) -> g0.
#define QKPV_LDS (32 * SROW_STRIDE * 2 + 8192)  // 94720 B

__global__ __launch_bounds__(256, 1) void k_qkpv(
    const unsigned short* __restrict__ ctrb, const unsigned short* __restrict__ MgtB,
    const unsigned short* __restrict__ Vgt, const unsigned short* __restrict__ G0tB,
    const float* __restrict__ ctr, float* __restrict__ ycen,
    float* __restrict__ g0g) {
    extern __shared__ char smem2[];
    unsigned short* Srow = (unsigned short*)smem2;      // [32][1352] S then P
    char* Ys = smem2 + 32 * SROW_STRIDE * 2;            // [32][256B] Tg then Y
    __shared__ float mxs[32], invs[32];
    int blk = blockIdx.x, b = blockIdx.y;
    int mb = blk * 32;
    int tid = threadIdx.x, wid = tid >> 6, lane = tid & 63;
    int lr = lane & 15, lg = lane >> 4;

    // Phase A: Tg tile = ctr[mb..mb+32) @ Mglob -> Ys (swizzled)
    {
        int nb = wid * 32;
        f32x4 tg[2][2] = {};
        const unsigned short* Cb = ctrb + ((size_t)b * NWIN + mb) * 128;
        #pragma unroll
        for (int ks = 0; ks < 4; ++ks) {
            int k = ks * 32 + lg * 8;
            bfrag b0 = *(const bfrag*)(Cb + lr * 128 + k);
            bfrag b1 = *(const bfrag*)(Cb + (16 + lr) * 128 + k);
            bfrag m0 = *(const bfrag*)(MgtB + (nb + lr) * 128 + k);
            bfrag m1 = *(const bfrag*)(MgtB + (nb + 16 + lr) * 128 + k);
            tg[0][0] = MFMA16(m0, b0, tg[0][0], 0, 0, 0);
            tg[0][1] = MFMA16(m0, b1, tg[0][1], 0, 0, 0);
            tg[1][0] = MFMA16(m1, b0, tg[1][0], 0, 0, 0);
            tg[1][1] = MFMA16(m1, b1, tg[1][1], 0, 0, 0);
        }
        #pragma unroll
        for (int ni = 0; ni < 2; ++ni)
            #pragma unroll
            for (int mj = 0; mj < 2; ++mj) {
                int n0 = nb + ni * 16 + 4 * lg;
                int m = mj * 16 + lr;
                int2 v; v.x = pack2(tg[ni][mj][0], tg[ni][mj][1]);
                v.y = pack2(tg[ni][mj][2], tg[ni][mj][3]);
                *(int2*)(Ys + m * 256 + ((2 * n0) ^ ((m & 7) << 4))) = v;
            }
    }
    __syncthreads();

    // Phase B: scores over all 1344 keys; A-frags from LDS Tg tile
    {
        int wm = (wid & 1) * 16, wn = (wid >> 1) * 32;
        for (int tile = 0; tile < 21; ++tile) {
            int nb = tile * 64 + wn;
            f32x4 acc[2] = {};
            #pragma unroll
            for (int ks = 0; ks < 4; ++ks) {
                int k = ks * 32 + lg * 8;
                bfrag a = ld256(Ys, wm + lr, k);
                #pragma unroll
                for (int nt = 0; nt < 2; ++nt) {
                    bfrag bb = *(const bfrag*)(ctrb + ((size_t)b * NWIN + nb + nt * 16 + lr) * 128 + k);
                    acc[nt] = MFMA16(a, bb, acc[nt], 0, 0, 0);
                }
            }
            #pragma unroll
            for (int nt = 0; nt < 2; ++nt) {
                int col = nb + nt * 16 + lr;
                #pragma unroll
                for (int r = 0; r < 4; ++r)
                    Srow[(wm + 4 * lg + r) * SROW_STRIDE + col] = f2b(acc[nt][r]);
            }
        }
    }
    __syncthreads();

    // Phase C: row max / sum, then in-place normalize (pad cols zeroed)
    {
        int row = tid >> 3, sub = tid & 7;
        const unsigned short* sr = Srow + row * SROW_STRIDE;
        float mx = -1e30f;
        for (int c = sub; c < 1344; c += 8) mx = fmaxf(mx, b2f(sr[c]));
        mx = fmaxf(mx, __shfl_xor(mx, 1));
        mx = fmaxf(mx, __shfl_xor(mx, 2));
        mx = fmaxf(mx, __shfl_xor(mx, 4));
        float sum = 0.f;
        for (int c = sub; c < 1344; c += 8) sum += __expf((b2f(sr[c]) - mx) * SCALE);
        sum += __shfl_xor(sum, 1);
        sum += __shfl_xor(sum, 2);
        sum += __shfl_xor(sum, 4);
        if (sub == 0) { mxs[row] = mx; invs[row] = 1.0f / sum; }
    }
    __syncthreads();
    for (int idx = tid; idx < 32 * (SROW_STRIDE / 8); idx += 256) {
        int row = idx / (SROW_STRIDE / 8), c8 = idx % (SROW_STRIDE / 8);
        float mx = mxs[row], inv = invs[row];
        unsigned short* sp = Srow + row * SROW_STRIDE + c8 * 8;
        unsigned short o[8];
        #pragma unroll
        for (int e = 0; e < 8; ++e) {
            int c = c8 * 8 + e;
            float p = (c < 1344) ? __expf((b2f(sp[e]) - mx) * SCALE) * inv : 0.f;
            o[e] = f2b(p);
        }
        *(int4*)sp = *(int4*)o;
    }
    __syncthreads();

    // Phase D: Y^T = Vgt x P^T (P from LDS, 42 exact iters); ycen + Ys stage
    {
        int cb = wid * 32;
        f32x4 acc[2][2] = {};
        const unsigned short* Vb = Vgt + (size_t)b * 128 * NP;
        for (int it = 0; it < 42; ++it) {
            int k = it * 32 + lg * 8;
            bfrag a0 = *(const bfrag*)(Vb + (size_t)(cb + lr) * NP + k);
            bfrag a1 = *(const bfrag*)(Vb + (size_t)(cb + 16 + lr) * NP + k);
            bfrag b0 = *(const bfrag*)(Srow + lr * SROW_STRIDE + k);
            bfrag b1 = *(const bfrag*)(Srow + (16 + lr) * SROW_STRIDE + k);
            acc[0][0] = MFMA16(a0, b0, acc[0][0], 0, 0, 0);
            acc[0][1] = MFMA16(a0, b1, acc[0][1], 0, 0, 0);
            acc[1][0] = MFMA16(a1, b0, acc[1][0], 0, 0, 0);
            acc[1][1] = MFMA16(a1, b1, acc[1][1], 0, 0, 0);
        }
        #pragma unroll
        for (int ci = 0; ci < 2; ++ci)
            #pragma unroll
            for (int mj = 0; mj < 2; ++mj) {
                int c0 = cb + ci * 16 + 4 * lg;
                int mr = mj * 16 + lr;
                int m = mb + mr;
                size_t base = ((size_t)b * NWIN + m) * 128 + c0;
                float4 cv = *(const float4*)(ctr + base);
                float4 y;
                y.x = acc[ci][mj][0] * cv.x;
                y.y = acc[ci][mj][1] * cv.y;
                y.z = acc[ci][mj][2] * cv.z;
                y.w = acc[ci][mj][3] * cv.w;
                *(float4*)(ycen + base) = y;
                int2 pv; pv.x = pack2(y.x, y.y); pv.y = pack2(y.z, y.w);
                *(int2*)(Ys + mr * 256 + ((2 * c0) ^ ((mr & 7) << 4))) = pv;
            }
    }
    __syncthreads();

    // Phase E: g0 = Y @ G0
    {
        int nb = wid * 32;
        f32x4 g[2][2] = {};
        #pragma unroll
        for (int ks = 0; ks < 4; ++ks) {
            int k = ks * 32 + lg * 8;
            bfrag a0 = *(const bfrag*)(G0tB + (nb + lr) * 128 + k);
            bfrag a1 = *(const bfrag*)(G0tB + (nb + 16 + lr) * 128 + k);
            bfrag b0 = ld256(Ys, lr, k);
            bfrag b1 = ld256(Ys, 16 + lr, k);
            g[0][0] = MFMA16(a0, b0, g[0][0], 0, 0, 0);
            g[0][1] = MFMA16(a0, b1, g[0][1], 0, 0, 0);
            g[1][0] = MFMA16(a1, b0, g[1][0], 0, 0, 0);
            g[1][1] = MFMA16(a1, b1, g[1][1], 0, 0, 0);
        }
        #pragma unroll
        for (int ni = 0; ni < 2; ++ni)
            #pragma unroll
            for (int mj = 0; mj < 2; ++mj) {
                int m = mb + mj * 16 + lr;
                int n0 = nb + ni * 16 + 4 * lg;
                #pragma unroll
                for (int r = 0; r < 4; ++r)
                    g0g[((size_t)b * NWIN + m) * 128 + n0 + r] = g[ni][mj][r];
            }
    }
}

// ---------- K5: fused local window attention via MFMA (80 KB, 2 blocks/CU) ----
// 5 barriers; P stored inside XM row t (wave-private).
#define XB_OFF 0
#define WT_OFF 16384
#define XM_OFF 49152
#define VT_OFF 65536
#define SMEM_SZ 81920

__global__ __launch_bounds__(256, 2) void k_local_mfma(
    const float* __restrict__ f0, const float* __restrict__ f1,
    const float* __restrict__ f2,
    const unsigned short* __restrict__ MtB,
    const unsigned short* __restrict__ WvltB,
    const unsigned short* __restrict__ G1tB,
    const float* __restrict__ g0g, const float* __restrict__ ycen,
    float* __restrict__ out) {
    extern __shared__ char smem[];
    char* Xb = smem + XB_OFF;    // X; yl in-place during phase 4
    char* Wt = smem + WT_OFF;    // Mt -> Wvlt -> G1t
    char* XMb = smem + XM_OFF;   // XM; P lives in row t's first 128 B (wave-private)
    char* Vt = smem + VT_OFF;

    int w = blockIdx.x, b = blockIdx.y;
    const float* f; int p0, HW, obase;
    window_src(w * WT, f0, f1, f2, f, p0, HW, obase);

    int tid = threadIdx.x;
    int wid = tid >> 6, lane = tid & 63;
    int lr = lane & 15, lg = lane >> 4;

    // ---- phase 0: stage X (f32->bf16 swizzled) + Mt weights ----
    {
        int t0 = tid & 63, cq = tid >> 6;
        const float* src = f + (size_t)(b * 128 + cq * 32) * HW + p0 + t0;
        float xv[32];
        #pragma unroll
        for (int i = 0; i < 32; ++i) xv[i] = src[(size_t)i * HW];
        int4 wreg[8];
        const int4* wsrc = (const int4*)MtB;
        #pragma unroll
        for (int j = 0; j < 8; ++j) wreg[j] = wsrc[j * 256 + tid];
        #pragma unroll
        for (int j = 0; j < 4; ++j) {
            int c0 = cq * 32 + j * 8;
            int4 v;
            v.x = pack2(xv[j * 8 + 0], xv[j * 8 + 1]);
            v.y = pack2(xv[j * 8 + 2], xv[j * 8 + 3]);
            v.z = pack2(xv[j * 8 + 4], xv[j * 8 + 5]);
            v.w = pack2(xv[j * 8 + 6], xv[j * 8 + 7]);
            *(int4*)(Xb + t0 * 256 + ((2 * c0) ^ ((t0 & 7) << 4))) = v;
        }
        #pragma unroll
        for (int j = 0; j < 8; ++j) {
            int ci = j * 256 + tid, n = ci >> 4, pos = ci & 15;
            *(int4*)(Wt + n * 256 + ((pos * 16) ^ ((n & 7) << 4))) = wreg[j];
        }
    }
    __syncthreads();  // B1

    int t = 16 * wid + lr;

    // ---- phase 1: XM^T = Mt(A,LDS) x X(B) -> XMb (wave-private rows) ----
    {
        f32x4 acc[8] = {};
        #pragma unroll
        for (int ks = 0; ks < 4; ++ks) {
            int k = ks * 32 + lg * 8;
            bfrag xb = ld256(Xb, t, k);
            #pragma unroll
            for (int ct = 0; ct < 8; ++ct) {
                bfrag am = ld256(Wt, 16 * ct + lr, k);
                acc[ct] = MFMA16(am, xb, acc[ct], 0, 0, 0);
            }
        }
        #pragma unroll
        for (int ct = 0; ct < 8; ++ct) {
            int c0 = 16 * ct + 4 * lg;
            int2 v; v.x = pack2(acc[ct][0], acc[ct][1]); v.y = pack2(acc[ct][2], acc[ct][3]);
            *(int2*)(XMb + t * 256 + ((2 * c0) ^ ((t & 7) << 4))) = v;
        }
    }
    __syncthreads();  // B2

    // ---- phase 2: S^T + softmax; P overwrites own XM row (no barrier); Wvlt ----
    {
        int4 wreg[8];
        const int4* wsrc = (const int4*)WvltB;
        #pragma unroll
        for (int j = 0; j < 8; ++j) wreg[j] = wsrc[j * 256 + tid];

        f32x4 s[4] = {};
        #pragma unroll
        for (int ks = 0; ks < 4; ++ks) {
            int k = ks * 32 + lg * 8;
            bfrag bxm = ld256(XMb, t, k);
            #pragma unroll
            for (int ut = 0; ut < 4; ++ut) {
                bfrag ax = ld256(Xb, 16 * ut + lr, k);
                s[ut] = MFMA16(ax, bxm, s[ut], 0, 0, 0);
            }
        }
        float m = -1e30f;
        #pragma unroll
        for (int ut = 0; ut < 4; ++ut)
            #pragma unroll
            for (int r = 0; r < 4; ++r) m = fmaxf(m, s[ut][r]);
        m = fmaxf(m, __shfl_xor(m, 16));
        m = fmaxf(m, __shfl_xor(m, 32));
        float sum = 0.f;
        float e[4][4];
        #pragma unroll
        for (int ut = 0; ut < 4; ++ut)
            #pragma unroll
            for (int r = 0; r < 4; ++r) {
                e[ut][r] = __expf((s[ut][r] - m) * SCALE);
                sum += e[ut][r];
            }
        sum += __shfl_xor(sum, 16);
        sum += __shfl_xor(sum, 32);
        float pinv = 1.0f / sum;
        #pragma unroll
        for (int ut = 0; ut < 4; ++ut) {
            int u0 = 16 * ut + 4 * lg;
            int2 v;
            v.x = pack2(e[ut][0] * pinv, e[ut][1] * pinv);
            v.y = pack2(e[ut][2] * pinv, e[ut][3] * pinv);
            *(int2*)(XMb + t * 256 + ((2 * u0) ^ ((t & 7) << 4))) = v;
        }
        #pragma unroll
        for (int j = 0; j < 8; ++j) {
            int ci = j * 256 + tid, n = ci >> 4, pos = ci & 15;
            *(int4*)(Wt + n * 256 + ((pos * 16) ^ ((n & 7) << 4))) = wreg[j];
        }
    }
    __syncthreads();  // B3 (Wvlt visible)

    // ---- phase 3: V^T = X(A) x Wvlt(B,LDS) -> Vt; issue G1t loads ----
    int4 wregG[8];
    {
        const int4* wsrc = (const int4*)G1tB;
        #pragma unroll
        for (int j = 0; j < 8; ++j) wregG[j] = wsrc[j * 256 + tid];

        f32x4 vacc[8] = {};
        #pragma unroll
        for (int ks = 0; ks < 4; ++ks) {
            int k = ks * 32 + lg * 8;
            bfrag ax = ld256(Xb, t, k);
            #pragma unroll
            for (int ct = 0; ct < 8; ++ct) {
                bfrag bw = ld256(Wt, 16 * ct + lr, k);
                vacc[ct] = MFMA16(ax, bw, vacc[ct], 0, 0, 0);
            }
        }
        #pragma unroll
        for (int ct = 0; ct < 8; ++ct) {
            int c = 16 * ct + lr;
            int u0 = 16 * wid + 4 * lg;
            int2 v; v.x = pack2(vacc[ct][0], vacc[ct][1]); v.y = pack2(vacc[ct][2], vacc[ct][3]);
            *(int2*)(Vt + c * 128 + ((2 * u0) ^ ((c & 7) << 4))) = v;
        }
    }
    __syncthreads();  // B4

    // ---- phase 4: stage G1t; Y^T = Vt(A) x P(B); yl = Y*X in-place; yg/g0 ----
    float yl[8][4];
    float4 yg4[8], g04[8];
    {
        #pragma unroll
        for (int j = 0; j < 8; ++j) {
            int ci = j * 256 + tid, n = ci >> 4, pos = ci & 15;
            *(int4*)(Wt + n * 256 + ((pos * 16) ^ ((n & 7) << 4))) = wregG[j];
        }
        size_t rbase = ((size_t)b * NWIN + w) * 128 + 4 * lg;
        #pragma unroll
        for (int nt = 0; nt < 8; ++nt) {
            yg4[nt] = *(const float4*)(ycen + rbase + 16 * nt);
            g04[nt] = *(const float4*)(g0g + rbase + 16 * nt);
        }
        f32x4 y[8] = {};
        #pragma unroll
        for (int us = 0; us < 2; ++us) {
            int u = us * 32 + lg * 8;
            bfrag bp = ld256(XMb, t, u);  // P (stride-256, own row)
            #pragma unroll
            for (int ct = 0; ct < 8; ++ct) {
                bfrag av = ld128(Vt, 16 * ct + lr, u);
                y[ct] = MFMA16(av, bp, y[ct], 0, 0, 0);
            }
        }
        #pragma unroll
        for (int ct = 0; ct < 8; ++ct) {
            int c0 = 16 * ct + 4 * lg;
            int2 xw = *(const int2*)(Xb + t * 256 + ((2 * c0) ^ ((t & 7) << 4)));
            float x0 = b2f((unsigned short)(xw.x & 0xffff));
            float x1 = b2f((unsigned short)((unsigned)xw.x >> 16));
            float x2 = b2f((unsigned short)(xw.y & 0xffff));
            float x3 = b2f((unsigned short)((unsigned)xw.y >> 16));
            yl[ct][0] = y[ct][0] * x0;
            yl[ct][1] = y[ct][1] * x1;
            yl[ct][2] = y[ct][2] * x2;
            yl[ct][3] = y[ct][3] * x3;
            int2 v; v.x = pack2(yl[ct][0], yl[ct][1]); v.y = pack2(yl[ct][2], yl[ct][3]);
            *(int2*)(Xb + t * 256 + ((2 * c0) ^ ((t & 7) << 4))) = v;  // in-place yl
        }
    }
    __syncthreads();  // B5

    // ---- phase 5: G^T = G1t(A,LDS) x yl(B); alpha; blend + store ----
    {
        f32x4 g[8] = {};
        #pragma unroll
        for (int ks = 0; ks < 4; ++ks) {
            int k = ks * 32 + lg * 8;
            bfrag byl = ld256(Xb, t, k);  // yl
            #pragma unroll
            for (int nt = 0; nt < 8; ++nt) {
                bfrag ag = ld256(Wt, 16 * nt + lr, k);
                g[nt] = MFMA16(ag, byl, g[nt], 0, 0, 0);
            }
        }
        #pragma unroll
        for (int nt = 0; nt < 8; ++nt) {
            float gv[4] = {g04[nt].x, g04[nt].y, g04[nt].z, g04[nt].w};
            float yv4[4] = {yg4[nt].x, yg4[nt].y, yg4[nt].z, yg4[nt].w};
            #pragma unroll
            for (int r = 0; r < 4; ++r) {
                int c = 16 * nt + 4 * lg + r;
                float a = 1.0f / (1.0f + __expf(-(g[nt][r] + gv[r])));
                float yv = a * yv4[r] + (1.0f - a) * yl[nt][r];
                out[obase + (size_t)(b * 128 + c) * HW + p0 + t] = yv;
            }
        }
    }
}

// ---------- K6/K7 v5: conv3x3 + PixelShuffle + residual, MFMA fp16 ----------
// NOC=128 per block (acc[8][2], VGPR ~145) -> 3 blocks/CU for latency hiding.
// Register double-buffered direct-L2 weight A-fragments (v4 structure).
template <int H, int W>
__global__ __launch_bounds__(256, 3) void k_conv_mfma(
    const float* __restrict__ in, const _Float16* __restrict__ Wcv,
    float* __restrict__ out) {
    constexpr int TXN = W / 32;
    int tile = blockIdx.x;
    int ty = tile / TXN, tx = tile % TXN;
    int y0 = ty * 4, x0 = tx * 32;
    int ob = blockIdx.y * 128;
    int b = blockIdx.z;

    __shared__ __align__(16) char sXs[16384];  // 204 rows x 80B, slot swz (row>>3)&1

    int tid = threadIdx.x;
    int wid = tid >> 6, lane = tid & 63;
    int lr = lane & 15, lg = lane >> 4;

    f32x4 acc[8][2] = {};

    int sy = tid / 34, sx = tid - sy * 34;
    int gy = y0 + sy - 1, gx = x0 + sx - 1;
    bool act = tid < 204;
    bool ok = act && gy >= 0 && gy < H && gx >= 0 && gx < W;
    const float* gp = in + (size_t)b * 128 * H * W + (size_t)gy * W + gx;
    int xswz = (tid >> 3) & 1;

    const _Float16* wbase = Wcv + (size_t)(ob + lr) * 32 + lg * 8;

    hfrag afC[2], afN[2];
    #pragma unroll
    for (int n = 0; n < 2; ++n)
        afC[n] = *(const hfrag*)(wbase + (size_t)(wid * 2 + n) * 512);

    if (act) {
        float xv[32];
        if (ok) {
            #pragma unroll
            for (int ic = 0; ic < 32; ++ic) xv[ic] = gp[(size_t)ic * H * W];
        } else {
            #pragma unroll
            for (int ic = 0; ic < 32; ++ic) xv[ic] = 0.f;
        }
        #pragma unroll
        for (int s = 0; s < 4; ++s) {
            _Float16 hh[8];
            #pragma unroll
            for (int e = 0; e < 8; ++e) hh[e] = (_Float16)xv[s * 8 + e];
            *(int4*)(sXs + tid * 80 + ((s ^ xswz) << 4)) = *(int4*)hh;
        }
    }
    __syncthreads();

    for (int ics = 0; ics < 4; ++ics) {
        if (ics) {
            __syncthreads();
            if (act) {
                float xv[32];
                if (ok) {
                    #pragma unroll
                    for (int ic = 0; ic < 32; ++ic)
                        xv[ic] = gp[(size_t)(ics * 32 + ic) * H * W];
                } else {
                    #pragma unroll
                    for (int ic = 0; ic < 32; ++ic) xv[ic] = 0.f;
                }
                #pragma unroll
                for (int s = 0; s < 4; ++s) {
                    _Float16 hh[8];
                    #pragma unroll
                    for (int e = 0; e < 8; ++e) hh[e] = (_Float16)xv[s * 8 + e];
                    *(int4*)(sXs + tid * 80 + ((s ^ xswz) << 4)) = *(int4*)hh;
                }
            }
            __syncthreads();
        }
        #pragma unroll
        for (int tap = 0; tap < 9; ++tap) {
            int kg = ics * 9 + tap;
            if (tap < 8 || ics < 3) {
                const _Float16* ws = wbase + (size_t)(kg + 1) * 16384;
                #pragma unroll
                for (int n = 0; n < 2; ++n)
                    afN[n] = *(const hfrag*)(ws + (size_t)(wid * 2 + n) * 512);
            }
            int dy = tap / 3, dx = tap - dy * 3;
            hfrag bf[8];
            #pragma unroll
            for (int m = 0; m < 8; ++m) {
                int row = ((m >> 1) + dy) * 34 + (m & 1) * 16 + lr + dx;
                bf[m] = *(const hfrag*)(sXs + row * 80 + ((lg ^ ((row >> 3) & 1)) << 4));
            }
            #pragma unroll
            for (int m = 0; m < 8; ++m)
                #pragma unroll
                for (int n = 0; n < 2; ++n)
                    acc[m][n] = MFMA16H(afC[n], bf[m], acc[m][n], 0, 0, 0);
            #pragma unroll
            for (int n = 0; n < 2; ++n) afC[n] = afN[n];
        }
    }

    float* outb = out + (size_t)b * 128 * 4 * H * W;
    #pragma unroll
    for (int n = 0; n < 2; ++n) {
        int oc0 = ob + (wid * 2 + n) * 16 + lg * 4;
        int c = oc0 >> 2;
        #pragma unroll
        for (int mr = 0; mr < 4; ++mr) {
            int py = y0 + mr;
            #pragma unroll
            for (int i2 = 0; i2 < 2; ++i2) {
                size_t rowb = ((size_t)c * (2 * H) + 2 * py + i2) * (2 * W);
                float2* p0 = (float2*)(outb + rowb + 2 * (x0 + lr));
                float2 v0 = *p0;
                v0.x += acc[2 * mr][n][i2 * 2 + 0];
                v0.y += acc[2 * mr][n][i2 * 2 + 1];
                *p0 = v0;
                float2* p1 = (float2*)(outb + rowb + 2 * (x0 + 16 + lr));
                float2 v1 = *p1;
                v1.x += acc[2 * mr + 1][n][i2 * 2 + 0];
                v1.y += acc[2 * mr + 1][n][i2 * 2 + 1];
                *p1 = v1;
            }
        }
    }
}

extern "C" void kernel_launch(void* const* d_in, const int* in_sizes, int n_in,
                              void* d_out, int out_size, void* d_ws, size_t ws_size,
                              hipStream_t stream) {
    const float* f0 = (const float*)d_in[0];
    const float* f1 = (const float*)d_in[1];
    const float* f2 = (const float*)d_in[2];
    const float* Wq = (const float*)d_in[3];
    const float* Wk = (const float*)d_in[4];
    const float* Wv = (const float*)d_in[5];
    const float* Wql = (const float*)d_in[6];
    const float* Wkl = (const float*)d_in[7];
    const float* Wvl = (const float*)d_in[8];
    const float* gate_w = (const float*)d_in[9];
    const float* conv0 = (const float*)d_in[10];
    const float* conv1 = (const float*)d_in[11];
    float* out = (float*)d_out;
    float* ws = (float*)d_ws;

    float* ctr = ws;                      // 688128 f32
    float* ycen = ctr + 688128;           // 688128 f32
    float* g0g = ycen + 688128;           // 688128 f32
    unsigned short* MtB = (unsigned short*)(g0g + 688128);   // 16384 bf16
    unsigned short* WvltB = MtB + 16384;                     // 16384 bf16
    unsigned short* G1tB = WvltB + 16384;                    // 16384 bf16
    unsigned short* G0tB = G1tB + 16384;                     // 16384 bf16
    unsigned short* MgtB = G0tB + 16384;                     // 16384 bf16
    unsigned short* WvtB = MgtB + 16384;                     // 16384 bf16
    _Float16* Wcv0 = (_Float16*)(WvtB + 16384);              // 589824 f16
    _Float16* Wcv1 = Wcv0 + 589824;                          // 589824 f16
    unsigned short* ctrb = (unsigned short*)(Wcv1 + 589824); // 688128 bf16
    unsigned short* Vgt = ctrb + 688128;                     // 4*128*NP bf16

    hipFuncSetAttribute((const void*)k_local_mfma,
                        hipFuncAttributeMaxDynamicSharedMemorySize, SMEM_SZ);
    hipFuncSetAttribute((const void*)k_qkpv,
                        hipFuncAttributeMaxDynamicSharedMemorySize, QKPV_LDS);

    k_prep_all<<<dim3(2304, 3), 256, 0, stream>>>(
        conv0, conv1, Wcv0, Wcv1, Wql, Wkl, Wvl, gate_w, Wq, Wk, Wv,
        MtB, WvltB, G1tB, G0tB, MgtB, WvtB);
    k_centers<<<dim3(NWIN, 4), 256, 0, stream>>>(f0, f1, f2, ctr, ctrb);
    k_vg<<<dim3(NWIN / 32, 4), 256, 0, stream>>>(ctrb, WvtB, Vgt);
    k_qkpv<<<dim3(NWIN / 32, 4), 256, QKPV_LDS, stream>>>(
        ctrb, MgtB, Vgt, G0tB, ctr, ycen, g0g);
    k_local_mfma<<<dim3(NWIN, 4), 256, SMEM_SZ, stream>>>(
        f0, f1, f2, MtB, WvltB, G1tB, g0g, ycen, out);
    k_conv_mfma<64, 64><<<dim3(32, 4, 4), 256, 0, stream>>>(out + OUT0, Wcv0, out + OUT1);
    k_conv_mfma<128, 128><<<dim3(128, 4, 4), 256, 0, stream>>>(out + OUT1, Wcv1, out + OUT2);
}